// Round 12
// baseline (410.455 us; speedup 1.0000x reference)
//
#include <hip/hip_runtime.h>
#include <hip/hip_bf16.h>
#include <math.h>

#define LAYERS 2
#define HIDDEN 512
#define FFN_DIM 2048
#define HEADS 8
#define SLEN 2048
#define BSZ 2
#define MROWS 4096
#define ATT_SCALING 0.125f
#define LN_EPS 1e-5f
#define SCALE_BASE 512.0f
#define LOG2E 1.4426950408889634f

typedef unsigned short u16;
typedef unsigned int u32;
typedef __attribute__((ext_vector_type(8))) short bf16x8;   // 8 bf16 = 4 VGPR
typedef __attribute__((ext_vector_type(4))) float f32x4;
typedef __attribute__((ext_vector_type(16))) float f32x16;

__device__ __forceinline__ float bf2f(u16 u) {
    union { u32 i; float f; } v; v.i = ((u32)u) << 16; return v.f;
}
__device__ __forceinline__ u16 f2bf(float f) {
    union { float f; u32 i; } v; v.f = f;
    u32 r = v.i + 0x7FFFu + ((v.i >> 16) & 1u);   // RNE
    return (u16)(r >> 16);
}
__device__ __forceinline__ u32 pk2bf(float a, float b) {   // packed RNE cvt
    union { __hip_bfloat162 h; u32 u; } v;
    v.h = __float22bfloat162_rn(make_float2(a, b));
    return v.u;
}
__device__ __forceinline__ u32 cvtpk(float a, float b) {   // HW packed cvt (T12)
    u32 r;
    asm("v_cvt_pk_bf16_f32 %0, %1, %2" : "=v"(r) : "v"(a), "v"(b));
    return r;
}
__device__ __forceinline__ void async16(const void* g, void* l) {
    __builtin_amdgcn_global_load_lds((const __attribute__((address_space(1))) void*)g,
                                     (__attribute__((address_space(3))) void*)l, 16, 0, 0);
}

// ---------------------------------------------------------------------------
// Fused prep: all 12 weight transposes (fp32 [K][N] -> bf16 [N][K]) +
// x fp32 -> (fp32 residual, bf16) + xpos cos/sin table. One dispatch.
// Block ranges: [0,7168) wtrans, [7168,9216) cvt_x, [9216,9472) xpos_table.
// ---------------------------------------------------------------------------
__global__ __launch_bounds__(256) void prep_kernel(const float* __restrict__ x,
                                                   const float* __restrict__ Wq,
                                                   const float* __restrict__ Wk,
                                                   const float* __restrict__ Wv,
                                                   const float* __restrict__ Wo,
                                                   const float* __restrict__ W1,
                                                   const float* __restrict__ W2,
                                                   char* __restrict__ w,
                                                   float* __restrict__ Af,
                                                   u16* __restrict__ Ab,
                                                   float2* __restrict__ tab) {
    const size_t MB1 = 1u << 20;
    const int bid = blockIdx.x;
    const int tid = threadIdx.x;
    __shared__ float t[32][33];

    if (bid < 7168) {
        int l = bid / 3584;
        int tt = bid % 3584;
        u16* WqkvT = (u16*)(w + 48 * MB1 + (size_t)l * 2 * MB1);
        u16* WoT   = (u16*)(w + 52 * MB1 + (size_t)l * 1 * MB1);
        u16* W1T   = (u16*)(w + 54 * MB1 + (size_t)l * 2 * MB1);
        u16* W2T   = (u16*)(w + 58 * MB1 + (size_t)l * 2 * MB1);
        const float* src; u16* dst; int K, N, tix;
        if (tt < 256)       { src = Wq + (size_t)l * 512 * 512;  dst = WqkvT;              K = 512;  N = 512;  tix = tt; }
        else if (tt < 512)  { src = Wk + (size_t)l * 512 * 512;  dst = WqkvT + 512 * 512;  K = 512;  N = 512;  tix = tt - 256; }
        else if (tt < 1024) { src = Wv + (size_t)l * 512 * 1024; dst = WqkvT + 1024 * 512; K = 512;  N = 1024; tix = tt - 512; }
        else if (tt < 1536) { src = Wo + (size_t)l * 1024 * 512; dst = WoT;                K = 1024; N = 512;  tix = tt - 1024; }
        else if (tt < 2560) { src = W1 + (size_t)l * 512 * 2048; dst = W1T;                K = 512;  N = 2048; tix = tt - 1536; }
        else                { src = W2 + (size_t)l * 2048 * 512; dst = W2T;                K = 2048; N = 512;  tix = tt - 2560; }
        int ntx = N >> 5;
        int n0 = (tix % ntx) * 32, k0 = (tix / ntx) * 32;
        int tx = tid & 31, ty = tid >> 5;
#pragma unroll
        for (int i = 0; i < 4; i++)
            t[ty + 8 * i][tx] = src[(size_t)(k0 + ty + 8 * i) * N + n0 + tx];
        __syncthreads();
#pragma unroll
        for (int i = 0; i < 4; i++)
            dst[(size_t)(n0 + ty + 8 * i) * K + k0 + tx] = f2bf(t[tx][ty + 8 * i]);
    } else if (bid < 9216) {
        int i = ((bid - 7168) * 256 + tid) * 4;
        float4 v = *(const float4*)(x + i);
        *(float4*)(Af + i) = v;
        uint2 p;
        p.x = pk2bf(v.x, v.y);
        p.y = pk2bf(v.z, v.w);
        *(uint2*)(Ab + i) = p;
    } else {
        int idx = (bid - 9216) * 256 + tid;     // 65536 entries
        int j = idx & 31;
        int s = idx >> 5;
        float base = (2.0f * j + 0.4f * 64.0f) / (1.4f * 64.0f);
        float pos = (float)(s - 1024);
        float scale = powf(base, pos / SCALE_BASE);
        float inv_freq = powf(10000.0f, -(float)j / 32.0f);
        float ang = (float)s * inv_freq;
        tab[idx] = make_float2(cosf(ang) * scale, sinf(ang) * scale);
    }
}

// ---------------------------------------------------------------------------
// V transpose only (round-12: xpos fused into QKV GEMM epilogue).
// V cols of QKV -> VT. 1024 blocks (was 5120 with the xpos half).
// ---------------------------------------------------------------------------
__global__ __launch_bounds__(256) void vtrans_kernel(const u16* __restrict__ QKV,
                                                     u16* __restrict__ VT) {
    const int tid = threadIdx.x;
    __shared__ u16 t[64][65];

    int v = blockIdx.x;                 // 1024 blocks
    int bz = v & 15;                    // b*8 + h
    int vy = (v >> 4) & 1;              // v-tile
    int sx = v >> 5;                    // s-tile (32)
    int b = bz >> 3, h = bz & 7;
    int s0 = sx * 64, v0 = vy * 64;
#pragma unroll
    for (int i = 0; i < 16; i++) {
        int e = tid + i * 256; int r = e >> 6, c = e & 63;      // r: s, c: v
        t[r][c] = QKV[(size_t)(b * SLEN + s0 + r) * 2048 + 1024 + h * 128 + v0 + c];
    }
    __syncthreads();
#pragma unroll
    for (int i = 0; i < 16; i++) {
        int e = tid + i * 256; int r = e >> 6, c = e & 63;      // r: v, c: s
        VT[(size_t)((b * 8 + h) * 128 + v0 + r) * 2048 + s0 + c] = t[c][r];
    }
}

// ---------------------------------------------------------------------------
// MFMA GEMM, software-pipelined, BK64, optional 2-way split-K (bias added by
// split 0 only). WT is [N][K] bf16. Split-K partials written BF16.
// Round-12: optional fused xPos epilogue (XPOS=1): for col<1024 (Q,K), the
// rotation pairs cols (2j,2j+1) which sit in adjacent lanes (col parity ==
// l15 parity) -> partner via shfl_xor(v,1). Q (col<512) additionally *LOG2E.
// Branches are BLOCK-uniform (tn multiple of 128; 512/1024 are multiples of
// 128) so the shfl executes convergently. Rotation now applies to fp32
// pre-rounding accumulator values (one fewer bf16 round-trip than before).
// ---------------------------------------------------------------------------
template <int BM, int BN, int BK, int WM, int OUTF32, int BIAS, int RELU,
          int NSPLIT, int WPE, int XPOS>
__global__ __launch_bounds__(256, WPE) void gemm_mfma(const u16* __restrict__ A,
                                                 const u16* __restrict__ WT,
                                                 const float* __restrict__ bias,
                                                 void* __restrict__ C0,
                                                 void* __restrict__ C1,
                                                 const float2* __restrict__ tab,
                                                 int M, int N, int K) {
    constexpr int WN  = 4 / WM;
    constexpr int AM  = BM / (WM * 16);
    constexpr int AN  = BN / (WN * 16);
    constexpr int KO  = BK / 32;
    constexpr int AIT = BM * BK / 2048;
    constexpr int BIT = BN * BK / 2048;
    constexpr int KB8 = BK / 8;

    __shared__ u16 As[2][BM * BK];
    __shared__ u16 Bs[2][BN * BK];

    const int tid  = threadIdx.x;
    const int wave = tid >> 6;
    const int lane = tid & 63;
    const int quad = lane >> 4;
    const int l15  = lane & 15;
    const int wm = wave % WM;
    const int wn = wave / WM;

    const int tm = blockIdx.y * BM;
    const int tn = blockIdx.x * BN;
    const int z  = (NSPLIT > 1) ? blockIdx.z : 0;
    const int Ksub = K / NSPLIT;
    const int k0g  = z * Ksub;

    auto issue = [&](int kt, int buf) {
#pragma unroll
        for (int it = 0; it < AIT; it++) {
            int cid = it * 256 + tid;
            async16(A + (size_t)(tm + cid / KB8) * K + k0g + kt + (cid % KB8) * 8,
                    (char*)As[buf] + (it * 256 + wave * 64) * 16);
        }
#pragma unroll
        for (int it = 0; it < BIT; it++) {
            int cid = it * 256 + tid;
            async16(WT + (size_t)(tn + cid / KB8) * K + k0g + kt + (cid % KB8) * 8,
                    (char*)Bs[buf] + (it * 256 + wave * 64) * 16);
        }
    };

    f32x4 acc[AM][AN];
#pragma unroll
    for (int i = 0; i < AM; i++)
#pragma unroll
        for (int j = 0; j < AN; j++) acc[i][j] = (f32x4){0.f, 0.f, 0.f, 0.f};

    const int nk = Ksub / BK;
    issue(0, 0);

    for (int t = 0; t < nk; t++) {
        __syncthreads();             // implicit vmcnt(0) drain: loads(t) done
        if (t + 1 < nk) issue((t + 1) * BK, (t + 1) & 1);
        const int buf = t & 1;

        bf16x8 af[KO][AM], bfr[KO][AN];
#pragma unroll
        for (int ko = 0; ko < KO; ko++) {
#pragma unroll
            for (int i = 0; i < AM; i++)
                af[ko][i] = *(const bf16x8*)((const char*)As[buf] +
                    (((wm * (AM * 16) + i * 16 + l15) * KB8) + ko * 4 + quad) * 16);
#pragma unroll
            for (int j = 0; j < AN; j++)
                bfr[ko][j] = *(const bf16x8*)((const char*)Bs[buf] +
                    (((wn * (AN * 16) + j * 16 + l15) * KB8) + ko * 4 + quad) * 16);
        }
#pragma unroll
        for (int ko = 0; ko < KO; ko++)
#pragma unroll
            for (int i = 0; i < AM; i++)
#pragma unroll
                for (int j = 0; j < AN; j++)
                    acc[i][j] = __builtin_amdgcn_mfma_f32_16x16x32_bf16(
                        af[ko][i], bfr[ko][j], acc[i][j], 0, 0, 0);
    }

    void* Cout = (NSPLIT > 1 && z) ? C1 : C0;
#pragma unroll
    for (int i = 0; i < AM; i++) {
#pragma unroll
        for (int j = 0; j < AN; j++) {
            int col = tn + wn * (AN * 16) + j * 16 + l15;
            float bv = (BIAS && z == 0) ? bias[col] : 0.0f;
#pragma unroll
            for (int r = 0; r < 4; r++) {
                int row = tm + wm * (AM * 16) + i * 16 + quad * 4 + r;
                float v = acc[i][j][r] + bv;
                if (RELU) v = fmaxf(v, 0.0f);
                if (XPOS) {
                    if (col < 1024) {            // block-uniform branch
                        int s  = row & (SLEN - 1);
                        int jp = (col & 63) >> 1;
                        float2 cssn = tab[s * 32 + jp];
                        float partner = __shfl_xor(v, 1, 64);
                        float rot = (l15 & 1) ? (v * cssn.x + partner * cssn.y)
                                              : (v * cssn.x - partner * cssn.y);
                        if (col < 512) rot *= LOG2E;   // block-uniform
                        v = rot;
                    }
                }
                if (OUTF32) ((float*)Cout)[(size_t)row * N + col] = v;
                else        ((u16*)Cout)[(size_t)row * N + col] = f2bf(v);
            }
        }
    }
}

// ---------------------------------------------------------------------------
// MFMA flash attention v12 (validated 53.5-56us): 32x32 MFMA, permlane
// P-build, 2-buffer + __syncthreads, cvt_pk, tree reductions, 3-way split-K.
// At its structural floor (r9: +50% occupancy -> flat). Unchanged.
// ---------------------------------------------------------------------------
__global__ __launch_bounds__(256, 3) void flash_attn_mfma(const u16* __restrict__ QKV,
                                                          const u16* __restrict__ VT,
                                                          u16* __restrict__ OP0,
                                                          u16* __restrict__ OP1,
                                                          u16* __restrict__ OP2,
                                                          float* __restrict__ MLW) {
    const int h  = blockIdx.x;           // XCD swizzle: x = head
    const int q0 = blockIdx.y * 128;
    const int bz = blockIdx.z;           // b*3 + split
    const int b  = bz / 3;
    const int split = bz - b * 3;
    const int tid  = threadIdx.x;
    const int wave = tid >> 6;
    const int lane = tid & 63;
    const int l31  = lane & 31;
    const int hi   = lane >> 5;
    const int swz  = (l31 & 7) ^ ((l31 >> 3) << 1);   // S(row) for row=l31 mod 32

    __shared__ u16 Ks[2][64 * 64];   // [row=key 0..63][64 d], 128B rows
    __shared__ u16 Vs[2][128 * 64];  // [row=v 0..127][64 keys] (48 KB total)

    const int tcnt = (split == 2) ? 10 : 11;   // 11+11+10 = 32 tiles of 64
    const int kb0  = split * 704;              // 11*64

    // hoisted per-thread staging source pointers (rule #21 inverse swizzle)
    const u16* kp[2];
    const u16* vp[4];
#pragma unroll
    for (int it = 0; it < 2; it++) {
        int cid = it * 256 + tid;            // 512 chunks = 64 rows x 8
        int row = cid >> 3;
        int lc  = (cid & 7) ^ (row & 7) ^ (((row >> 3) & 3) << 1);
        kp[it] = QKV + (size_t)(b * SLEN + kb0 + row) * 2048 + 512 + h * 64 + lc * 8;
    }
#pragma unroll
    for (int it = 0; it < 4; it++) {
        int cid = it * 256 + tid;            // 1024 chunks = 128 rows x 8
        int row = cid >> 3;
        int lc  = (cid & 7) ^ (row & 7) ^ (((row >> 3) & 3) << 1);
        vp[it] = VT + (size_t)((b * 8 + h) * 128 + row) * 2048 + kb0 + lc * 8;
    }

    auto issueKV = [&](int buf) {
#pragma unroll
        for (int it = 0; it < 2; it++) {
            async16(kp[it], (char*)Ks[buf] + (it * 256 + wave * 64) * 16);
            kp[it] += 64 * 2048;             // next 64-key tile
        }
#pragma unroll
        for (int it = 0; it < 4; it++) {
            async16(vp[it], (char*)Vs[buf] + (it * 256 + wave * 64) * 16);
            vp[it] += 64;                    // next 64-key column chunk
        }
    };

    // Q B-fragments: col=q=l31 (row q0+wave*32+l31), k-chunk hi: 4 d-chunks
    bf16x8 qf[4];
    {
        const u16* p = QKV + (size_t)(b * SLEN + q0 + wave * 32 + l31) * 2048 +
                       h * 64 + hi * 8;
#pragma unroll
        for (int dc = 0; dc < 4; dc++) qf[dc] = *(const bf16x8*)(p + dc * 16);
    }

    f32x16 o_acc[4];   // o_acc[rb][reg] = O^T[v=rb*32+crow(reg,hi)][q=l31]
#pragma unroll
    for (int rb = 0; rb < 4; rb++)
#pragma unroll
        for (int r = 0; r < 16; r++) o_acc[rb][r] = 0.f;
    float m = -1e30f;
    float l = 0.f;

    issueKV(0);

    for (int ti = 0; ti < tcnt; ti++) {
        __syncthreads();                 // implicit vmcnt(0): tiles(ti) landed
        if (ti + 1 < tcnt) issueKV((ti + 1) & 1);
        const int buf = ti & 1;

        // S^T = K x Q : st[kb][reg] = S[key=kb*32+crow(reg,hi)][q=l31]
        f32x16 st[2];
#pragma unroll
        for (int kb = 0; kb < 2; kb++)
#pragma unroll
            for (int r = 0; r < 16; r++) st[kb][r] = 0.f;
        __builtin_amdgcn_s_setprio(1);
#pragma unroll
        for (int dc = 0; dc < 4; dc++)
#pragma unroll
            for (int kb = 0; kb < 2; kb++) {
                bf16x8 kf = *(const bf16x8*)((const char*)Ks[buf] +
                    ((kb * 32 + l31) * 8 + ((dc * 2 + hi) ^ swz)) * 16);
                st[kb] = __builtin_amdgcn_mfma_f32_32x32x16_bf16(kf, qf[dc],
                                                                 st[kb], 0, 0, 0);
            }
        __builtin_amdgcn_s_setprio(0);

        // softmax max: pairwise tree (depth 5) + one cross-half exchange
        float fm[16];
#pragma unroll
        for (int r = 0; r < 16; r++) fm[r] = fmaxf(st[0][r], st[1][r]);
#pragma unroll
        for (int s = 8; s > 0; s >>= 1)
#pragma unroll
            for (int r = 0; r < s; r++) fm[r] = fmaxf(fm[r], fm[r + s]);
        float mx = fmaxf(fm[0], __shfl_xor(fm[0], 32, 64));

        float mnew = fmaxf(m, mx);
        float alpha = exp2f(m - mnew);
        m = mnew;

        // exp + 4-chain sum (depth 8)
        float s0 = 0.f, s1 = 0.f, s2 = 0.f, s3 = 0.f;
#pragma unroll
        for (int kb = 0; kb < 2; kb++)
#pragma unroll
            for (int r = 0; r < 16; r += 4) {
                float p0 = exp2f(st[kb][r + 0] - mnew);
                float p1 = exp2f(st[kb][r + 1] - mnew);
                float p2 = exp2f(st[kb][r + 2] - mnew);
                float p3 = exp2f(st[kb][r + 3] - mnew);
                st[kb][r + 0] = p0; st[kb][r + 1] = p1;
                st[kb][r + 2] = p2; st[kb][r + 3] = p3;
                s0 += p0; s1 += p1; s2 += p2; s3 += p3;
            }
        float ls = (s0 + s1) + (s2 + s3);
        ls += __shfl_xor(ls, 32, 64);
        l = l * alpha + ls;

        // rescale O^T (alpha uniform across the lane's q column)
#pragma unroll
        for (int rb = 0; rb < 4; rb++)
#pragma unroll
            for (int r = 0; r < 16; r++) o_acc[rb][r] *= alpha;

        // PV: B-frag = P^T[key][q] built via cvt_pk + permlane32_swap (T12)
#pragma unroll
        for (int kc = 0; kc < 4; kc++) {
            const int kb = kc >> 1, o = (kc & 1) * 8;
            u32 a1 = cvtpk(st[kb][o + 0], st[kb][o + 1]);
            u32 b1 = cvtpk(st[kb][o + 4], st[kb][o + 5]);
            u32 a2 = cvtpk(st[kb][o + 2], st[kb][o + 3]);
            u32 b2 = cvtpk(st[kb][o + 6], st[kb][o + 7]);
            asm volatile("v_permlane32_swap_b32 %0, %1" : "+v"(a1), "+v"(b1));
            asm volatile("v_permlane32_swap_b32 %0, %1" : "+v"(a2), "+v"(b2));
            union { u32 u[4]; bf16x8 v; } pf;
            pf.u[0] = a1; pf.u[1] = a2; pf.u[2] = b1; pf.u[3] = b2;
            __builtin_amdgcn_s_setprio(1);
#pragma unroll
            for (int rb = 0; rb < 4; rb++) {
                bf16x8 vb = *(const bf16x8*)((const char*)Vs[buf] +
                    ((rb * 32 + l31) * 8 + ((kc * 2 + hi) ^ swz)) * 16);
                o_acc[rb] = __builtin_amdgcn_mfma_f32_32x32x16_bf16(vb, pf.v,
                                                                    o_acc[rb], 0, 0, 0);
            }
            __builtin_amdgcn_s_setprio(0);
        }
    }

    // epilogue: write l-normalized partial O/l; scalar logw = m + log2(l).
    const int q = q0 + wave * 32 + l31;
    if (lane < 32)
        MLW[((size_t)(b * 3 + split) * 8 + h) * 2048 + q] = m + __log2f(l);
    const float invl = 1.0f / l;
    u16* OP = (split == 0) ? OP0 : ((split == 1) ? OP1 : OP2);
    const size_t rstride = (split == 2) ? 2048 : 1024;   // OP2 = QKV V-cols
    size_t rowbase = ((size_t)(b * SLEN + q)) * rstride + h * 128;
#pragma unroll
    for (int rb = 0; rb < 4; rb++)
#pragma unroll
        for (int i = 0; i < 8; i++) {
            int v = rb * 32 + ((2 * i) & 3) + 8 * (i >> 1) + 4 * hi;
            *(u32*)(OP + rowbase + v) =
                pk2bf(o_acc[rb][2 * i] * invl, o_acc[rb][2 * i + 1] * invl);
        }
}

// ---------------------------------------------------------------------------
// Merge the three l-normalized split-K partials (8 elems/thread, uint4):
// out = ATT_SCALING * Sum_s O_s * 2^(logw_s - M) / Sum_s 2^(logw_s - M)
// P2 is strided (QKV V-columns, row stride 2048).
// ---------------------------------------------------------------------------
__global__ __launch_bounds__(256) void attn_combine(const u16* __restrict__ P0,
                                                    const u16* __restrict__ P1,
                                                    const u16* __restrict__ P2,
                                                    const float* __restrict__ MLW,
                                                    u16* __restrict__ AT) {
    int idx = (blockIdx.x * 256 + threadIdx.x) * 8;   // 4096*1024 total
    int col = idx & 1023;
    int row = idx >> 10;                        // b*2048 + q
    int h = col >> 7;
    int b = row >> 11, q = row & 2047;
    float g0 = MLW[((size_t)(b * 3 + 0) * 8 + h) * 2048 + q];
    float g1 = MLW[((size_t)(b * 3 + 1) * 8 + h) * 2048 + q];
    float g2 = MLW[((size_t)(b * 3 + 2) * 8 + h) * 2048 + q];
    float M = fmaxf(g0, fmaxf(g1, g2));
    float e0 = exp2f(g0 - M), e1 = exp2f(g1 - M), e2 = exp2f(g2 - M);
    float norm = ATT_SCALING / (e0 + e1 + e2);
    e0 *= norm; e1 *= norm; e2 *= norm;

    uint4 a = *(const uint4*)(P0 + idx);
    uint4 c = *(const uint4*)(P1 + idx);
    uint4 d = *(const uint4*)(P2 + (size_t)row * 2048 + col);
    uint4 o;
    u32 au[4] = {a.x, a.y, a.z, a.w};
    u32 cu[4] = {c.x, c.y, c.z, c.w};
    u32 du[4] = {d.x, d.y, d.z, d.w};
    u32 ou[4];
#pragma unroll
    for (int k = 0; k < 4; k++) {
        float r0 = bf2f((u16)(au[k] & 0xffff)) * e0 + bf2f((u16)(cu[k] & 0xffff)) * e1 +
                   bf2f((u16)(du[k] & 0xffff)) * e2;
        float r1 = bf2f((u16)(au[k] >> 16)) * e0 + bf2f((u16)(cu[k] >> 16)) * e1 +
                   bf2f((u16)(du[k] >> 16)) * e2;
        ou[k] = pk2bf(r0, r1);
    }
    o.x = ou[0]; o.y = ou[1]; o.z = ou[2]; o.w = ou[3];
    *(uint4*)(AT + idx) = o;
}

// ---------------------------------------------------------------------------
// LN(X + R0 + R1) * g + be : X fp32, R0/R1 BF16 split-K partials, fp32 +
// bf16 out. One wave per row (lane owns 8 cols), float4/uint4 loads,
// shfl_xor reductions, zero LDS / barriers.
// ---------------------------------------------------------------------------
__global__ __launch_bounds__(256) void addln_kernel(const float* __restrict__ X,
                                                    const u16* __restrict__ R0,
                                                    const u16* __restrict__ R1,
                                                    const float* __restrict__ g,
                                                    const float* __restrict__ be,
                                                    float* __restrict__ dstf,
                                                    u16* __restrict__ dstb) {
    const int tid  = threadIdx.x;
    const int wave = tid >> 6;
    const int lane = tid & 63;
    const int row  = blockIdx.x * 4 + wave;
    size_t off = (size_t)row * HIDDEN + lane * 8;

    float4 a0 = *(const float4*)(X + off),  a1 = *(const float4*)(X + off + 4);
    uint4 p = *(const uint4*)(R0 + off);
    uint4 q = *(const uint4*)(R1 + off);
    u32 pu[4] = {p.x, p.y, p.z, p.w};
    u32 qu[4] = {q.x, q.y, q.z, q.w};
    float v[8];
    v[0] = a0.x + bf2f((u16)(pu[0] & 0xffff)) + bf2f((u16)(qu[0] & 0xffff));
    v[1] = a0.y + bf2f((u16)(pu[0] >> 16))    + bf2f((u16)(qu[0] >> 16));
    v[2] = a0.z + bf2f((u16)(pu[1] & 0xffff)) + bf2f((u16)(qu[1] & 0xffff));
    v[3] = a0.w + bf2f((u16)(pu[1] >> 16))    + bf2f((u16)(qu[1] >> 16));
    v[4] = a1.x + bf2f((u16)(pu[2] & 0xffff)) + bf2f((u16)(qu[2] & 0xffff));
    v[5] = a1.y + bf2f((u16)(pu[2] >> 16))    + bf2f((u16)(qu[2] >> 16));
    v[6] = a1.z + bf2f((u16)(pu[3] & 0xffff)) + bf2f((u16)(qu[3] & 0xffff));
    v[7] = a1.w + bf2f((u16)(pu[3] >> 16))    + bf2f((u16)(qu[3] >> 16));

    float s = ((v[0] + v[1]) + (v[2] + v[3])) + ((v[4] + v[5]) + (v[6] + v[7]));
#pragma unroll
    for (int d = 1; d < 64; d <<= 1) s += __shfl_xor(s, d, 64);
    float mu = s * (1.0f / HIDDEN);

    float t = 0.f;
#pragma unroll
    for (int j = 0; j < 8; j++) { float dv = v[j] - mu; v[j] = dv; t += dv * dv; }
#pragma unroll
    for (int d = 1; d < 64; d <<= 1) t += __shfl_xor(t, d, 64);
    float rstd = rsqrtf(t * (1.0f / HIDDEN) + LN_EPS);

    float4 g0 = *(const float4*)(g + lane * 8),  g1 = *(const float4*)(g + lane * 8 + 4);
    float4 b0 = *(const float4*)(be + lane * 8), b1 = *(const float4*)(be + lane * 8 + 4);
    float o[8];
    o[0] = v[0] * rstd * g0.x + b0.x; o[1] = v[1] * rstd * g0.y + b0.y;
    o[2] = v[2] * rstd * g0.z + b0.z; o[3] = v[3] * rstd * g0.w + b0.w;
    o[4] = v[4] * rstd * g1.x + b1.x; o[5] = v[5] * rstd * g1.y + b1.y;
    o[6] = v[6] * rstd * g1.z + b1.z; o[7] = v[7] * rstd * g1.w + b1.w;

    *(float4*)(dstf + off)     = make_float4(o[0], o[1], o[2], o[3]);
    *(float4*)(dstf + off + 4) = make_float4(o[4], o[5], o[6], o[7]);
    uint4 ob;
    ob.x = pk2bf(o[0], o[1]); ob.y = pk2bf(o[2], o[3]);
    ob.z = pk2bf(o[4], o[5]); ob.w = pk2bf(o[6], o[7]);
    *(uint4*)(dstb + off) = ob;
}

// ---------------------------------------------------------------------------
extern "C" void kernel_launch(void* const* d_in, const int* in_sizes, int n_in,
                              void* d_out, int out_size, void* d_ws, size_t ws_size,
                              hipStream_t stream) {
    const float* x   = (const float*)d_in[0];
    const float* Wq  = (const float*)d_in[1];
    const float* Wk  = (const float*)d_in[2];
    const float* Wv  = (const float*)d_in[3];
    const float* Wo  = (const float*)d_in[4];
    const float* W1  = (const float*)d_in[5];
    const float* b1  = (const float*)d_in[6];
    const float* W2  = (const float*)d_in[7];
    const float* b2  = (const float*)d_in[8];
    const float* g1  = (const float*)d_in[9];
    const float* be1 = (const float*)d_in[10];
    const float* g2  = (const float*)d_in[11];
    const float* be2 = (const float*)d_in[12];
    float* out = (float*)d_out;

    // Workspace (63 MB):
    //  0-8   : R1f residual (fp32)
    //  8-16  : VTg -> Yf
    //  16-20 : OP1 -> PfA(bf16) -> F2a(bf16)
    //  20-24 : PfB(bf16) -> F2b(bf16)
    //  24-40 : QKV (V-cols double as OP2) -> F1
    //  40-48 : A_bf(40-44) -> OP0/AT -> Y_bf(40-44) -> A_bf
    //  48-62 : bf16 transposed weights ; 62-62.5 : xtab ; 62.5-63: MLW (384KB)
    const size_t MB = 1u << 20;
    char* w = (char*)d_ws;
    float*  R1f  = (float*)(w);
    u16*    VTg  = (u16*)(w + 8 * MB);
    float*  Yf   = (float*)(w + 8 * MB);
    u16*    OP1  = (u16*)(w + 16 * MB);
    u16*    PfA  = (u16*)(w + 16 * MB);
    u16*    F2a  = (u16*)(w + 16 * MB);
    u16*    PfB  = (u16*)(w + 20 * MB);
    u16*    F2b  = (u16*)(w + 20 * MB);
    u16*    QKV  = (u16*)(w + 24 * MB);
    u16*    F1   = (u16*)(w + 24 * MB);
    u16*    A_bf = (u16*)(w + 40 * MB);
    u16*    OP0  = (u16*)(w + 40 * MB);
    u16*    AT   = (u16*)(w + 40 * MB);
    u16*    Y_bf = (u16*)(w + 40 * MB);
    float2* xtab = (float2*)(w + 62 * MB);
    float*  MLW  = (float*)(w + 62 * MB + 512 * 1024);
    u16*    OP2  = QKV + 1024;           // dead V-columns, row stride 2048

    // One fused prep dispatch: 12 weight transposes + x convert + xpos table
    prep_kernel<<<9472, 256, 0, stream>>>(x, Wq, Wk, Wv, Wo, W1, W2,
                                          w, R1f, A_bf, xtab);

    for (int l = 0; l < LAYERS; l++) {
        u16* WqkvT = (u16*)(w + 48 * MB + (size_t)l * 2 * MB);
        u16* WoT   = (u16*)(w + 52 * MB + (size_t)l * 1 * MB);
        u16* W1T   = (u16*)(w + 54 * MB + (size_t)l * 2 * MB);
        u16* W2T   = (u16*)(w + 58 * MB + (size_t)l * 2 * MB);
        const float* b1_l  = b1 + (size_t)l * FFN_DIM;
        const float* b2_l  = b2 + (size_t)l * HIDDEN;
        const float* g1_l  = g1 + (size_t)l * HIDDEN;
        const float* be1_l = be1 + (size_t)l * HIDDEN;
        const float* g2_l  = g2 + (size_t)l * HIDDEN;
        const float* be2_l = be2 + (size_t)l * HIDDEN;

        // QKV = A_bf @ [Wq|Wk|Wv]  (bf16 out) with FUSED xPos epilogue
        // (Q rotated*LOG2E, K rotated, V passthrough), 128x128 BK64
        gemm_mfma<128, 128, 64, 2, 0, 0, 0, 1, 2, 1><<<dim3(16, 32), 256, 0, stream>>>(
            A_bf, WqkvT, nullptr, QKV, nullptr, xtab, MROWS, 2048, 512);

        // V transpose only (xpos now fused into the GEMM above)
        vtrans_kernel<<<1024, 256, 0, stream>>>(QKV, VTg);

        // flash attention: 3-way split-K, grid (h, qtile, b*3+split) = 768
        flash_attn_mfma<<<dim3(8, 16, 6), 256, 0, stream>>>(QKV, VTg, OP0, OP1,
                                                            OP2, MLW);
        attn_combine<<<MROWS * 1024 / 2048, 256, 0, stream>>>(OP0, OP1, OP2,
                                                              MLW, AT);

        // P = AT @ Wo: 128x64 BK64, 2-way split-K -> BF16 partials
        gemm_mfma<128, 64, 64, 2, 0, 0, 0, 2, 2, 0><<<dim3(8, 32, 2), 256, 0, stream>>>(
            AT, WoT, nullptr, PfA, PfB, nullptr, MROWS, 512, 1024);

        // Y = LN(A + P0 + P1), wave-per-row, bf16 partial reads
        addln_kernel<<<MROWS / 4, 256, 0, stream>>>(R1f, PfA, PfB, g1_l, be1_l, Yf, Y_bf);

        // F1 = relu(Y @ W1 + b1) (bf16 out), 128x128 BK64
        gemm_mfma<128, 128, 64, 2, 0, 1, 1, 1, 2, 0><<<dim3(16, 32), 256, 0, stream>>>(
            Y_bf, W1T, b1_l, F1, nullptr, nullptr, MROWS, 2048, 512);

        // F2 = F1 @ W2 + b2: 128x64 BK64, 2-way split-K -> BF16 partials
        gemm_mfma<128, 64, 64, 2, 0, 1, 0, 2, 2, 0><<<dim3(8, 32, 2), 256, 0, stream>>>(
            F1, W2T, b2_l, F2a, F2b, nullptr, MROWS, 512, 2048);

        // x_next = LN(Y + F2a + F2b), wave-per-row
        float* dstf = (l == LAYERS - 1) ? out : R1f;
        addln_kernel<<<MROWS / 4, 256, 0, stream>>>(Yf, F2a, F2b, g2_l, be2_l, dstf, A_bf);
    }
}

// Round 13
// 390.883 us; speedup vs baseline: 1.0501x; 1.0501x over previous
//
#include <hip/hip_runtime.h>
#include <hip/hip_bf16.h>
#include <math.h>

#define LAYERS 2
#define HIDDEN 512
#define FFN_DIM 2048
#define HEADS 8
#define SLEN 2048
#define BSZ 2
#define MROWS 4096
#define ATT_SCALING 0.125f
#define LN_EPS 1e-5f
#define SCALE_BASE 512.0f
#define LOG2E 1.4426950408889634f

typedef unsigned short u16;
typedef unsigned int u32;
typedef __attribute__((ext_vector_type(8))) short bf16x8;   // 8 bf16 = 4 VGPR
typedef __attribute__((ext_vector_type(4))) float f32x4;
typedef __attribute__((ext_vector_type(16))) float f32x16;

__device__ __forceinline__ float bf2f(u16 u) {
    union { u32 i; float f; } v; v.i = ((u32)u) << 16; return v.f;
}
__device__ __forceinline__ u16 f2bf(float f) {
    union { float f; u32 i; } v; v.f = f;
    u32 r = v.i + 0x7FFFu + ((v.i >> 16) & 1u);   // RNE
    return (u16)(r >> 16);
}
__device__ __forceinline__ u32 pk2bf(float a, float b) {   // packed RNE cvt
    union { __hip_bfloat162 h; u32 u; } v;
    v.h = __float22bfloat162_rn(make_float2(a, b));
    return v.u;
}
__device__ __forceinline__ u32 cvtpk(float a, float b) {   // HW packed cvt (T12)
    u32 r;
    asm("v_cvt_pk_bf16_f32 %0, %1, %2" : "=v"(r) : "v"(a), "v"(b));
    return r;
}
__device__ __forceinline__ void async16(const void* g, void* l) {
    __builtin_amdgcn_global_load_lds((const __attribute__((address_space(1))) void*)g,
                                     (__attribute__((address_space(3))) void*)l, 16, 0, 0);
}

// ---------------------------------------------------------------------------
// Fused prep: all 12 weight transposes (fp32 [K][N] -> bf16 [N][K]) +
// x fp32 -> (fp32 residual, bf16) + xpos cos/sin table. One dispatch.
// Block ranges: [0,7168) wtrans, [7168,9216) cvt_x, [9216,9472) xpos_table.
// ---------------------------------------------------------------------------
__global__ __launch_bounds__(256) void prep_kernel(const float* __restrict__ x,
                                                   const float* __restrict__ Wq,
                                                   const float* __restrict__ Wk,
                                                   const float* __restrict__ Wv,
                                                   const float* __restrict__ Wo,
                                                   const float* __restrict__ W1,
                                                   const float* __restrict__ W2,
                                                   char* __restrict__ w,
                                                   float* __restrict__ Af,
                                                   u16* __restrict__ Ab,
                                                   float2* __restrict__ tab) {
    const size_t MB1 = 1u << 20;
    const int bid = blockIdx.x;
    const int tid = threadIdx.x;
    __shared__ float t[32][33];

    if (bid < 7168) {
        int l = bid / 3584;
        int tt = bid % 3584;
        u16* WqkvT = (u16*)(w + 48 * MB1 + (size_t)l * 2 * MB1);
        u16* WoT   = (u16*)(w + 52 * MB1 + (size_t)l * 1 * MB1);
        u16* W1T   = (u16*)(w + 54 * MB1 + (size_t)l * 2 * MB1);
        u16* W2T   = (u16*)(w + 58 * MB1 + (size_t)l * 2 * MB1);
        const float* src; u16* dst; int K, N, tix;
        if (tt < 256)       { src = Wq + (size_t)l * 512 * 512;  dst = WqkvT;              K = 512;  N = 512;  tix = tt; }
        else if (tt < 512)  { src = Wk + (size_t)l * 512 * 512;  dst = WqkvT + 512 * 512;  K = 512;  N = 512;  tix = tt - 256; }
        else if (tt < 1024) { src = Wv + (size_t)l * 512 * 1024; dst = WqkvT + 1024 * 512; K = 512;  N = 1024; tix = tt - 512; }
        else if (tt < 1536) { src = Wo + (size_t)l * 1024 * 512; dst = WoT;                K = 1024; N = 512;  tix = tt - 1024; }
        else if (tt < 2560) { src = W1 + (size_t)l * 512 * 2048; dst = W1T;                K = 512;  N = 2048; tix = tt - 1536; }
        else                { src = W2 + (size_t)l * 2048 * 512; dst = W2T;                K = 2048; N = 512;  tix = tt - 2560; }
        int ntx = N >> 5;
        int n0 = (tix % ntx) * 32, k0 = (tix / ntx) * 32;
        int tx = tid & 31, ty = tid >> 5;
#pragma unroll
        for (int i = 0; i < 4; i++)
            t[ty + 8 * i][tx] = src[(size_t)(k0 + ty + 8 * i) * N + n0 + tx];
        __syncthreads();
#pragma unroll
        for (int i = 0; i < 4; i++)
            dst[(size_t)(n0 + ty + 8 * i) * K + k0 + tx] = f2bf(t[tx][ty + 8 * i]);
    } else if (bid < 9216) {
        int i = ((bid - 7168) * 256 + tid) * 4;
        float4 v = *(const float4*)(x + i);
        *(float4*)(Af + i) = v;
        uint2 p;
        p.x = pk2bf(v.x, v.y);
        p.y = pk2bf(v.z, v.w);
        *(uint2*)(Ab + i) = p;
    } else {
        int idx = (bid - 9216) * 256 + tid;     // 65536 entries
        int j = idx & 31;
        int s = idx >> 5;
        float base = (2.0f * j + 0.4f * 64.0f) / (1.4f * 64.0f);
        float pos = (float)(s - 1024);
        float scale = powf(base, pos / SCALE_BASE);
        float inv_freq = powf(10000.0f, -(float)j / 32.0f);
        float ang = (float)s * inv_freq;
        tab[idx] = make_float2(cosf(ang) * scale, sinf(ang) * scale);
    }
}

// ---------------------------------------------------------------------------
// Fused xPos (in-place on Q,K cols of QKV; Q scaled by LOG2E) + V transpose
// (V cols of QKV -> VT) — column-disjoint, no intra-kernel ordering needed.
// Block ranges: [0,4096) xpos, [4096,5120) vtrans.
// (r13: restored from r11 — the r12 GEMM-epilogue xpos fusion added 64
// uncoalesced table loads per thread and regressed +24us.)
// ---------------------------------------------------------------------------
__global__ __launch_bounds__(256) void xpos_vtrans(u16* __restrict__ QKV,
                                                   const float2* __restrict__ tab,
                                                   u16* __restrict__ VT) {
    const int bid = blockIdx.x;
    const int tid = threadIdx.x;
    __shared__ u16 t[64][65];

    if (bid < 4096) {
        int idx = bid * 256 + tid;   // 2^20
        int j = idx & 31;
        int h = (idx >> 5) & 7;
        int s = (idx >> 8) & 2047;
        int b = idx >> 19;

        float2 cssn = tab[s * 32 + j];
        float cs = cssn.x, sn = cssn.y;

        size_t off = (size_t)(b * SLEN + s) * 2048 + h * 64 + 2 * j;
        u32* pq = (u32*)(QKV + off);
        u32* pk = (u32*)(QKV + off + 512);

        u32 qv = *pq;
        float q0 = bf2f((u16)(qv & 0xffff)), q1 = bf2f((u16)(qv >> 16));
        *pq = pk2bf((q0 * cs - q1 * sn) * LOG2E, (q1 * cs + q0 * sn) * LOG2E);

        u32 kv = *pk;
        float k0 = bf2f((u16)(kv & 0xffff)), k1 = bf2f((u16)(kv >> 16));
        *pk = pk2bf(k0 * cs - k1 * sn, k1 * cs + k0 * sn);
    } else {
        int v = bid - 4096;                 // 1024 blocks
        int bz = v & 15;                    // b*8 + h
        int vy = (v >> 4) & 1;              // v-tile
        int sx = v >> 5;                    // s-tile (32)
        int b = bz >> 3, h = bz & 7;
        int s0 = sx * 64, v0 = vy * 64;
#pragma unroll
        for (int i = 0; i < 16; i++) {
            int e = tid + i * 256; int r = e >> 6, c = e & 63;      // r: s, c: v
            t[r][c] = QKV[(size_t)(b * SLEN + s0 + r) * 2048 + 1024 + h * 128 + v0 + c];
        }
        __syncthreads();
#pragma unroll
        for (int i = 0; i < 16; i++) {
            int e = tid + i * 256; int r = e >> 6, c = e & 63;      // r: v, c: s
            VT[(size_t)((b * 8 + h) * 128 + v0 + r) * 2048 + s0 + c] = t[c][r];
        }
    }
}

// ---------------------------------------------------------------------------
// MFMA GEMM, software-pipelined, BK64, optional 2-way split-K (bias added by
// split 0 only). WT is [N][K] bf16. Split-K partials written BF16 (OUTF32=0)
// to halve partial write + addln read traffic. (r11-validated config.)
// ---------------------------------------------------------------------------
template <int BM, int BN, int BK, int WM, int OUTF32, int BIAS, int RELU,
          int NSPLIT, int WPE>
__global__ __launch_bounds__(256, WPE) void gemm_mfma(const u16* __restrict__ A,
                                                 const u16* __restrict__ WT,
                                                 const float* __restrict__ bias,
                                                 void* __restrict__ C0,
                                                 void* __restrict__ C1,
                                                 int M, int N, int K) {
    constexpr int WN  = 4 / WM;
    constexpr int AM  = BM / (WM * 16);
    constexpr int AN  = BN / (WN * 16);
    constexpr int KO  = BK / 32;
    constexpr int AIT = BM * BK / 2048;
    constexpr int BIT = BN * BK / 2048;
    constexpr int KB8 = BK / 8;

    __shared__ u16 As[2][BM * BK];
    __shared__ u16 Bs[2][BN * BK];

    const int tid  = threadIdx.x;
    const int wave = tid >> 6;
    const int lane = tid & 63;
    const int quad = lane >> 4;
    const int l15  = lane & 15;
    const int wm = wave % WM;
    const int wn = wave / WM;

    const int tm = blockIdx.y * BM;
    const int tn = blockIdx.x * BN;
    const int z  = (NSPLIT > 1) ? blockIdx.z : 0;
    const int Ksub = K / NSPLIT;
    const int k0g  = z * Ksub;

    auto issue = [&](int kt, int buf) {
#pragma unroll
        for (int it = 0; it < AIT; it++) {
            int cid = it * 256 + tid;
            async16(A + (size_t)(tm + cid / KB8) * K + k0g + kt + (cid % KB8) * 8,
                    (char*)As[buf] + (it * 256 + wave * 64) * 16);
        }
#pragma unroll
        for (int it = 0; it < BIT; it++) {
            int cid = it * 256 + tid;
            async16(WT + (size_t)(tn + cid / KB8) * K + k0g + kt + (cid % KB8) * 8,
                    (char*)Bs[buf] + (it * 256 + wave * 64) * 16);
        }
    };

    f32x4 acc[AM][AN];
#pragma unroll
    for (int i = 0; i < AM; i++)
#pragma unroll
        for (int j = 0; j < AN; j++) acc[i][j] = (f32x4){0.f, 0.f, 0.f, 0.f};

    const int nk = Ksub / BK;
    issue(0, 0);

    for (int t = 0; t < nk; t++) {
        __syncthreads();             // implicit vmcnt(0) drain: loads(t) done
        if (t + 1 < nk) issue((t + 1) * BK, (t + 1) & 1);
        const int buf = t & 1;

        bf16x8 af[KO][AM], bfr[KO][AN];
#pragma unroll
        for (int ko = 0; ko < KO; ko++) {
#pragma unroll
            for (int i = 0; i < AM; i++)
                af[ko][i] = *(const bf16x8*)((const char*)As[buf] +
                    (((wm * (AM * 16) + i * 16 + l15) * KB8) + ko * 4 + quad) * 16);
#pragma unroll
            for (int j = 0; j < AN; j++)
                bfr[ko][j] = *(const bf16x8*)((const char*)Bs[buf] +
                    (((wn * (AN * 16) + j * 16 + l15) * KB8) + ko * 4 + quad) * 16);
        }
#pragma unroll
        for (int ko = 0; ko < KO; ko++)
#pragma unroll
            for (int i = 0; i < AM; i++)
#pragma unroll
                for (int j = 0; j < AN; j++)
                    acc[i][j] = __builtin_amdgcn_mfma_f32_16x16x32_bf16(
                        af[ko][i], bfr[ko][j], acc[i][j], 0, 0, 0);
    }

    void* Cout = (NSPLIT > 1 && z) ? C1 : C0;
#pragma unroll
    for (int i = 0; i < AM; i++) {
#pragma unroll
        for (int j = 0; j < AN; j++) {
            int col = tn + wn * (AN * 16) + j * 16 + l15;
            float bv = (BIAS && z == 0) ? bias[col] : 0.0f;
#pragma unroll
            for (int r = 0; r < 4; r++) {
                int row = tm + wm * (AM * 16) + i * 16 + quad * 4 + r;
                float v = acc[i][j][r] + bv;
                if (RELU) v = fmaxf(v, 0.0f);
                if (OUTF32) ((float*)Cout)[(size_t)row * N + col] = v;
                else        ((u16*)Cout)[(size_t)row * N + col] = f2bf(v);
            }
        }
    }
}

// ---------------------------------------------------------------------------
// MFMA flash attention v12 (validated 53.5-56us): 32x32 MFMA, permlane
// P-build, 2-buffer + __syncthreads, cvt_pk, tree reductions, 3-way split-K.
// At its structural floor (r9: +50% occupancy -> flat). Unchanged.
// ---------------------------------------------------------------------------
__global__ __launch_bounds__(256, 3) void flash_attn_mfma(const u16* __restrict__ QKV,
                                                          const u16* __restrict__ VT,
                                                          u16* __restrict__ OP0,
                                                          u16* __restrict__ OP1,
                                                          u16* __restrict__ OP2,
                                                          float* __restrict__ MLW) {
    const int h  = blockIdx.x;           // XCD swizzle: x = head
    const int q0 = blockIdx.y * 128;
    const int bz = blockIdx.z;           // b*3 + split
    const int b  = bz / 3;
    const int split = bz - b * 3;
    const int tid  = threadIdx.x;
    const int wave = tid >> 6;
    const int lane = tid & 63;
    const int l31  = lane & 31;
    const int hi   = lane >> 5;
    const int swz  = (l31 & 7) ^ ((l31 >> 3) << 1);   // S(row) for row=l31 mod 32

    __shared__ u16 Ks[2][64 * 64];   // [row=key 0..63][64 d], 128B rows
    __shared__ u16 Vs[2][128 * 64];  // [row=v 0..127][64 keys] (48 KB total)

    const int tcnt = (split == 2) ? 10 : 11;   // 11+11+10 = 32 tiles of 64
    const int kb0  = split * 704;              // 11*64

    // hoisted per-thread staging source pointers (rule #21 inverse swizzle)
    const u16* kp[2];
    const u16* vp[4];
#pragma unroll
    for (int it = 0; it < 2; it++) {
        int cid = it * 256 + tid;            // 512 chunks = 64 rows x 8
        int row = cid >> 3;
        int lc  = (cid & 7) ^ (row & 7) ^ (((row >> 3) & 3) << 1);
        kp[it] = QKV + (size_t)(b * SLEN + kb0 + row) * 2048 + 512 + h * 64 + lc * 8;
    }
#pragma unroll
    for (int it = 0; it < 4; it++) {
        int cid = it * 256 + tid;            // 1024 chunks = 128 rows x 8
        int row = cid >> 3;
        int lc  = (cid & 7) ^ (row & 7) ^ (((row >> 3) & 3) << 1);
        vp[it] = VT + (size_t)((b * 8 + h) * 128 + row) * 2048 + kb0 + lc * 8;
    }

    auto issueKV = [&](int buf) {
#pragma unroll
        for (int it = 0; it < 2; it++) {
            async16(kp[it], (char*)Ks[buf] + (it * 256 + wave * 64) * 16);
            kp[it] += 64 * 2048;             // next 64-key tile
        }
#pragma unroll
        for (int it = 0; it < 4; it++) {
            async16(vp[it], (char*)Vs[buf] + (it * 256 + wave * 64) * 16);
            vp[it] += 64;                    // next 64-key column chunk
        }
    };

    // Q B-fragments: col=q=l31 (row q0+wave*32+l31), k-chunk hi: 4 d-chunks
    bf16x8 qf[4];
    {
        const u16* p = QKV + (size_t)(b * SLEN + q0 + wave * 32 + l31) * 2048 +
                       h * 64 + hi * 8;
#pragma unroll
        for (int dc = 0; dc < 4; dc++) qf[dc] = *(const bf16x8*)(p + dc * 16);
    }

    f32x16 o_acc[4];   // o_acc[rb][reg] = O^T[v=rb*32+crow(reg,hi)][q=l31]
#pragma unroll
    for (int rb = 0; rb < 4; rb++)
#pragma unroll
        for (int r = 0; r < 16; r++) o_acc[rb][r] = 0.f;
    float m = -1e30f;
    float l = 0.f;

    issueKV(0);

    for (int ti = 0; ti < tcnt; ti++) {
        __syncthreads();                 // implicit vmcnt(0): tiles(ti) landed
        if (ti + 1 < tcnt) issueKV((ti + 1) & 1);
        const int buf = ti & 1;

        // S^T = K x Q : st[kb][reg] = S[key=kb*32+crow(reg,hi)][q=l31]
        f32x16 st[2];
#pragma unroll
        for (int kb = 0; kb < 2; kb++)
#pragma unroll
            for (int r = 0; r < 16; r++) st[kb][r] = 0.f;
        __builtin_amdgcn_s_setprio(1);
#pragma unroll
        for (int dc = 0; dc < 4; dc++)
#pragma unroll
            for (int kb = 0; kb < 2; kb++) {
                bf16x8 kf = *(const bf16x8*)((const char*)Ks[buf] +
                    ((kb * 32 + l31) * 8 + ((dc * 2 + hi) ^ swz)) * 16);
                st[kb] = __builtin_amdgcn_mfma_f32_32x32x16_bf16(kf, qf[dc],
                                                                 st[kb], 0, 0, 0);
            }
        __builtin_amdgcn_s_setprio(0);

        // softmax max: pairwise tree (depth 5) + one cross-half exchange
        float fm[16];
#pragma unroll
        for (int r = 0; r < 16; r++) fm[r] = fmaxf(st[0][r], st[1][r]);
#pragma unroll
        for (int s = 8; s > 0; s >>= 1)
#pragma unroll
            for (int r = 0; r < s; r++) fm[r] = fmaxf(fm[r], fm[r + s]);
        float mx = fmaxf(fm[0], __shfl_xor(fm[0], 32, 64));

        float mnew = fmaxf(m, mx);
        float alpha = exp2f(m - mnew);
        m = mnew;

        // exp + 4-chain sum (depth 8)
        float s0 = 0.f, s1 = 0.f, s2 = 0.f, s3 = 0.f;
#pragma unroll
        for (int kb = 0; kb < 2; kb++)
#pragma unroll
            for (int r = 0; r < 16; r += 4) {
                float p0 = exp2f(st[kb][r + 0] - mnew);
                float p1 = exp2f(st[kb][r + 1] - mnew);
                float p2 = exp2f(st[kb][r + 2] - mnew);
                float p3 = exp2f(st[kb][r + 3] - mnew);
                st[kb][r + 0] = p0; st[kb][r + 1] = p1;
                st[kb][r + 2] = p2; st[kb][r + 3] = p3;
                s0 += p0; s1 += p1; s2 += p2; s3 += p3;
            }
        float ls = (s0 + s1) + (s2 + s3);
        ls += __shfl_xor(ls, 32, 64);
        l = l * alpha + ls;

        // rescale O^T (alpha uniform across the lane's q column)
#pragma unroll
        for (int rb = 0; rb < 4; rb++)
#pragma unroll
            for (int r = 0; r < 16; r++) o_acc[rb][r] *= alpha;

        // PV: B-frag = P^T[key][q] built via cvt_pk + permlane32_swap (T12)
#pragma unroll
        for (int kc = 0; kc < 4; kc++) {
            const int kb = kc >> 1, o = (kc & 1) * 8;
            u32 a1 = cvtpk(st[kb][o + 0], st[kb][o + 1]);
            u32 b1 = cvtpk(st[kb][o + 4], st[kb][o + 5]);
            u32 a2 = cvtpk(st[kb][o + 2], st[kb][o + 3]);
            u32 b2 = cvtpk(st[kb][o + 6], st[kb][o + 7]);
            asm volatile("v_permlane32_swap_b32 %0, %1" : "+v"(a1), "+v"(b1));
            asm volatile("v_permlane32_swap_b32 %0, %1" : "+v"(a2), "+v"(b2));
            union { u32 u[4]; bf16x8 v; } pf;
            pf.u[0] = a1; pf.u[1] = a2; pf.u[2] = b1; pf.u[3] = b2;
            __builtin_amdgcn_s_setprio(1);
#pragma unroll
            for (int rb = 0; rb < 4; rb++) {
                bf16x8 vb = *(const bf16x8*)((const char*)Vs[buf] +
                    ((rb * 32 + l31) * 8 + ((kc * 2 + hi) ^ swz)) * 16);
                o_acc[rb] = __builtin_amdgcn_mfma_f32_32x32x16_bf16(vb, pf.v,
                                                                    o_acc[rb], 0, 0, 0);
            }
            __builtin_amdgcn_s_setprio(0);
        }
    }

    // epilogue: write l-normalized partial O/l; scalar logw = m + log2(l).
    const int q = q0 + wave * 32 + l31;
    if (lane < 32)
        MLW[((size_t)(b * 3 + split) * 8 + h) * 2048 + q] = m + __log2f(l);
    const float invl = 1.0f / l;
    u16* OP = (split == 0) ? OP0 : ((split == 1) ? OP1 : OP2);
    const size_t rstride = (split == 2) ? 2048 : 1024;   // OP2 = QKV V-cols
    size_t rowbase = ((size_t)(b * SLEN + q)) * rstride + h * 128;
#pragma unroll
    for (int rb = 0; rb < 4; rb++)
#pragma unroll
        for (int i = 0; i < 8; i++) {
            int v = rb * 32 + ((2 * i) & 3) + 8 * (i >> 1) + 4 * hi;
            *(u32*)(OP + rowbase + v) =
                pk2bf(o_acc[rb][2 * i] * invl, o_acc[rb][2 * i + 1] * invl);
        }
}

// ---------------------------------------------------------------------------
// Merge the three l-normalized split-K partials (8 elems/thread, uint4):
// out = ATT_SCALING * Sum_s O_s * 2^(logw_s - M) / Sum_s 2^(logw_s - M)
// P2 is strided (QKV V-columns, row stride 2048).
// ---------------------------------------------------------------------------
__global__ __launch_bounds__(256) void attn_combine(const u16* __restrict__ P0,
                                                    const u16* __restrict__ P1,
                                                    const u16* __restrict__ P2,
                                                    const float* __restrict__ MLW,
                                                    u16* __restrict__ AT) {
    int idx = (blockIdx.x * 256 + threadIdx.x) * 8;   // 4096*1024 total
    int col = idx & 1023;
    int row = idx >> 10;                        // b*2048 + q
    int h = col >> 7;
    int b = row >> 11, q = row & 2047;
    float g0 = MLW[((size_t)(b * 3 + 0) * 8 + h) * 2048 + q];
    float g1 = MLW[((size_t)(b * 3 + 1) * 8 + h) * 2048 + q];
    float g2 = MLW[((size_t)(b * 3 + 2) * 8 + h) * 2048 + q];
    float M = fmaxf(g0, fmaxf(g1, g2));
    float e0 = exp2f(g0 - M), e1 = exp2f(g1 - M), e2 = exp2f(g2 - M);
    float norm = ATT_SCALING / (e0 + e1 + e2);
    e0 *= norm; e1 *= norm; e2 *= norm;

    uint4 a = *(const uint4*)(P0 + idx);
    uint4 c = *(const uint4*)(P1 + idx);
    uint4 d = *(const uint4*)(P2 + (size_t)row * 2048 + col);
    uint4 o;
    u32 au[4] = {a.x, a.y, a.z, a.w};
    u32 cu[4] = {c.x, c.y, c.z, c.w};
    u32 du[4] = {d.x, d.y, d.z, d.w};
    u32 ou[4];
#pragma unroll
    for (int k = 0; k < 4; k++) {
        float r0 = bf2f((u16)(au[k] & 0xffff)) * e0 + bf2f((u16)(cu[k] & 0xffff)) * e1 +
                   bf2f((u16)(du[k] & 0xffff)) * e2;
        float r1 = bf2f((u16)(au[k] >> 16)) * e0 + bf2f((u16)(cu[k] >> 16)) * e1 +
                   bf2f((u16)(du[k] >> 16)) * e2;
        ou[k] = pk2bf(r0, r1);
    }
    o.x = ou[0]; o.y = ou[1]; o.z = ou[2]; o.w = ou[3];
    *(uint4*)(AT + idx) = o;
}

// ---------------------------------------------------------------------------
// LN(X + R0 + R1) * g + be : X fp32, R0/R1 BF16 split-K partials, fp32 +
// bf16 out. One wave per row (lane owns 8 cols), float4/uint4 loads,
// shfl_xor reductions, zero LDS / barriers.
// ---------------------------------------------------------------------------
__global__ __launch_bounds__(256) void addln_kernel(const float* __restrict__ X,
                                                    const u16* __restrict__ R0,
                                                    const u16* __restrict__ R1,
                                                    const float* __restrict__ g,
                                                    const float* __restrict__ be,
                                                    float* __restrict__ dstf,
                                                    u16* __restrict__ dstb) {
    const int tid  = threadIdx.x;
    const int wave = tid >> 6;
    const int lane = tid & 63;
    const int row  = blockIdx.x * 4 + wave;
    size_t off = (size_t)row * HIDDEN + lane * 8;

    float4 a0 = *(const float4*)(X + off),  a1 = *(const float4*)(X + off + 4);
    uint4 p = *(const uint4*)(R0 + off);
    uint4 q = *(const uint4*)(R1 + off);
    u32 pu[4] = {p.x, p.y, p.z, p.w};
    u32 qu[4] = {q.x, q.y, q.z, q.w};
    float v[8];
    v[0] = a0.x + bf2f((u16)(pu[0] & 0xffff)) + bf2f((u16)(qu[0] & 0xffff));
    v[1] = a0.y + bf2f((u16)(pu[0] >> 16))    + bf2f((u16)(qu[0] >> 16));
    v[2] = a0.z + bf2f((u16)(pu[1] & 0xffff)) + bf2f((u16)(qu[1] & 0xffff));
    v[3] = a0.w + bf2f((u16)(pu[1] >> 16))    + bf2f((u16)(qu[1] >> 16));
    v[4] = a1.x + bf2f((u16)(pu[2] & 0xffff)) + bf2f((u16)(qu[2] & 0xffff));
    v[5] = a1.y + bf2f((u16)(pu[2] >> 16))    + bf2f((u16)(qu[2] >> 16));
    v[6] = a1.z + bf2f((u16)(pu[3] & 0xffff)) + bf2f((u16)(qu[3] & 0xffff));
    v[7] = a1.w + bf2f((u16)(pu[3] >> 16))    + bf2f((u16)(qu[3] >> 16));

    float s = ((v[0] + v[1]) + (v[2] + v[3])) + ((v[4] + v[5]) + (v[6] + v[7]));
#pragma unroll
    for (int d = 1; d < 64; d <<= 1) s += __shfl_xor(s, d, 64);
    float mu = s * (1.0f / HIDDEN);

    float t = 0.f;
#pragma unroll
    for (int j = 0; j < 8; j++) { float dv = v[j] - mu; v[j] = dv; t += dv * dv; }
#pragma unroll
    for (int d = 1; d < 64; d <<= 1) t += __shfl_xor(t, d, 64);
    float rstd = rsqrtf(t * (1.0f / HIDDEN) + LN_EPS);

    float4 g0 = *(const float4*)(g + lane * 8),  g1 = *(const float4*)(g + lane * 8 + 4);
    float4 b0 = *(const float4*)(be + lane * 8), b1 = *(const float4*)(be + lane * 8 + 4);
    float o[8];
    o[0] = v[0] * rstd * g0.x + b0.x; o[1] = v[1] * rstd * g0.y + b0.y;
    o[2] = v[2] * rstd * g0.z + b0.z; o[3] = v[3] * rstd * g0.w + b0.w;
    o[4] = v[4] * rstd * g1.x + b1.x; o[5] = v[5] * rstd * g1.y + b1.y;
    o[6] = v[6] * rstd * g1.z + b1.z; o[7] = v[7] * rstd * g1.w + b1.w;

    *(float4*)(dstf + off)     = make_float4(o[0], o[1], o[2], o[3]);
    *(float4*)(dstf + off + 4) = make_float4(o[4], o[5], o[6], o[7]);
    uint4 ob;
    ob.x = pk2bf(o[0], o[1]); ob.y = pk2bf(o[2], o[3]);
    ob.z = pk2bf(o[4], o[5]); ob.w = pk2bf(o[6], o[7]);
    *(uint4*)(dstb + off) = ob;
}

// ---------------------------------------------------------------------------
extern "C" void kernel_launch(void* const* d_in, const int* in_sizes, int n_in,
                              void* d_out, int out_size, void* d_ws, size_t ws_size,
                              hipStream_t stream) {
    const float* x   = (const float*)d_in[0];
    const float* Wq  = (const float*)d_in[1];
    const float* Wk  = (const float*)d_in[2];
    const float* Wv  = (const float*)d_in[3];
    const float* Wo  = (const float*)d_in[4];
    const float* W1  = (const float*)d_in[5];
    const float* b1  = (const float*)d_in[6];
    const float* W2  = (const float*)d_in[7];
    const float* b2  = (const float*)d_in[8];
    const float* g1  = (const float*)d_in[9];
    const float* be1 = (const float*)d_in[10];
    const float* g2  = (const float*)d_in[11];
    const float* be2 = (const float*)d_in[12];
    float* out = (float*)d_out;

    // Workspace (63 MB):
    //  0-8   : R1f residual (fp32)
    //  8-16  : VTg -> Yf
    //  16-20 : OP1 -> PfA(bf16) -> F2a(bf16)
    //  20-24 : PfB(bf16) -> F2b(bf16)
    //  24-40 : QKV (V-cols double as OP2) -> F1
    //  40-48 : A_bf(40-44) -> OP0/AT -> Y_bf(40-44) -> A_bf
    //  48-62 : bf16 transposed weights ; 62-62.5 : xtab ; 62.5-63: MLW (384KB)
    const size_t MB = 1u << 20;
    char* w = (char*)d_ws;
    float*  R1f  = (float*)(w);
    u16*    VTg  = (u16*)(w + 8 * MB);
    float*  Yf   = (float*)(w + 8 * MB);
    u16*    OP1  = (u16*)(w + 16 * MB);
    u16*    PfA  = (u16*)(w + 16 * MB);
    u16*    F2a  = (u16*)(w + 16 * MB);
    u16*    PfB  = (u16*)(w + 20 * MB);
    u16*    F2b  = (u16*)(w + 20 * MB);
    u16*    QKV  = (u16*)(w + 24 * MB);
    u16*    F1   = (u16*)(w + 24 * MB);
    u16*    A_bf = (u16*)(w + 40 * MB);
    u16*    OP0  = (u16*)(w + 40 * MB);
    u16*    AT   = (u16*)(w + 40 * MB);
    u16*    Y_bf = (u16*)(w + 40 * MB);
    float2* xtab = (float2*)(w + 62 * MB);
    float*  MLW  = (float*)(w + 62 * MB + 512 * 1024);
    u16*    OP2  = QKV + 1024;           // dead V-columns, row stride 2048

    // One fused prep dispatch: 12 weight transposes + x convert + xpos table
    prep_kernel<<<9472, 256, 0, stream>>>(x, Wq, Wk, Wv, Wo, W1, W2,
                                          w, R1f, A_bf, xtab);

    for (int l = 0; l < LAYERS; l++) {
        u16* WqkvT = (u16*)(w + 48 * MB + (size_t)l * 2 * MB);
        u16* WoT   = (u16*)(w + 52 * MB + (size_t)l * 1 * MB);
        u16* W1T   = (u16*)(w + 54 * MB + (size_t)l * 2 * MB);
        u16* W2T   = (u16*)(w + 58 * MB + (size_t)l * 2 * MB);
        const float* b1_l  = b1 + (size_t)l * FFN_DIM;
        const float* b2_l  = b2 + (size_t)l * HIDDEN;
        const float* g1_l  = g1 + (size_t)l * HIDDEN;
        const float* be1_l = be1 + (size_t)l * HIDDEN;
        const float* g2_l  = g2 + (size_t)l * HIDDEN;
        const float* be2_l = be2 + (size_t)l * HIDDEN;

        // QKV = A_bf @ [Wq|Wk|Wv]  (bf16 out), 128x128 BK64, 512 blocks
        gemm_mfma<128, 128, 64, 2, 0, 0, 0, 1, 2><<<dim3(16, 32), 256, 0, stream>>>(
            A_bf, WqkvT, nullptr, QKV, nullptr, MROWS, 2048, 512);

        // fused xpos (Q,K) + V transpose
        xpos_vtrans<<<5120, 256, 0, stream>>>(QKV, xtab, VTg);

        // flash attention: 3-way split-K, grid (h, qtile, b*3+split) = 768
        flash_attn_mfma<<<dim3(8, 16, 6), 256, 0, stream>>>(QKV, VTg, OP0, OP1,
                                                            OP2, MLW);
        attn_combine<<<MROWS * 1024 / 2048, 256, 0, stream>>>(OP0, OP1, OP2,
                                                              MLW, AT);

        // P = AT @ Wo: 128x64 BK64, 2-way split-K -> BF16 partials
        gemm_mfma<128, 64, 64, 2, 0, 0, 0, 2, 2><<<dim3(8, 32, 2), 256, 0, stream>>>(
            AT, WoT, nullptr, PfA, PfB, MROWS, 512, 1024);

        // Y = LN(A + P0 + P1), wave-per-row, bf16 partial reads
        addln_kernel<<<MROWS / 4, 256, 0, stream>>>(R1f, PfA, PfB, g1_l, be1_l, Yf, Y_bf);

        // F1 = relu(Y @ W1 + b1) (bf16 out), 128x128 BK64
        gemm_mfma<128, 128, 64, 2, 0, 1, 1, 1, 2><<<dim3(16, 32), 256, 0, stream>>>(
            Y_bf, W1T, b1_l, F1, nullptr, MROWS, 2048, 512);

        // F2 = F1 @ W2 + b2: 128x64 BK64, 2-way split-K -> BF16 partials
        gemm_mfma<128, 64, 64, 2, 0, 1, 0, 2, 2><<<dim3(8, 32, 2), 256, 0, stream>>>(
            F1, W2T, b2_l, F2a, F2b, MROWS, 512, 2048);

        // x_next = LN(Y + F2a + F2b), wave-per-row
        float* dstf = (l == LAYERS - 1) ? out : R1f;
        addln_kernel<<<MROWS / 4, 256, 0, stream>>>(Yf, F2a, F2b, g2_l, be2_l, dstf, A_bf);
    }
}

// Round 14
// 385.533 us; speedup vs baseline: 1.0646x; 1.0139x over previous
//
#include <hip/hip_runtime.h>
#include <hip/hip_bf16.h>
#include <math.h>

#define LAYERS 2
#define HIDDEN 512
#define FFN_DIM 2048
#define HEADS 8
#define SLEN 2048
#define BSZ 2
#define MROWS 4096
#define ATT_SCALING 0.125f
#define LN_EPS 1e-5f
#define SCALE_BASE 512.0f
#define LOG2E 1.4426950408889634f

typedef unsigned short u16;
typedef unsigned int u32;
typedef __attribute__((ext_vector_type(8))) short bf16x8;   // 8 bf16 = 4 VGPR
typedef __attribute__((ext_vector_type(4))) float f32x4;
typedef __attribute__((ext_vector_type(16))) float f32x16;

__device__ __forceinline__ float bf2f(u16 u) {
    union { u32 i; float f; } v; v.i = ((u32)u) << 16; return v.f;
}
__device__ __forceinline__ u16 f2bf(float f) {
    union { float f; u32 i; } v; v.f = f;
    u32 r = v.i + 0x7FFFu + ((v.i >> 16) & 1u);   // RNE
    return (u16)(r >> 16);
}
__device__ __forceinline__ u32 pk2bf(float a, float b) {   // packed RNE cvt
    union { __hip_bfloat162 h; u32 u; } v;
    v.h = __float22bfloat162_rn(make_float2(a, b));
    return v.u;
}
__device__ __forceinline__ u32 cvtpk(float a, float b) {   // HW packed cvt (T12)
    u32 r;
    asm("v_cvt_pk_bf16_f32 %0, %1, %2" : "=v"(r) : "v"(a), "v"(b));
    return r;
}
__device__ __forceinline__ void async16(const void* g, void* l) {
    __builtin_amdgcn_global_load_lds((const __attribute__((address_space(1))) void*)g,
                                     (__attribute__((address_space(3))) void*)l, 16, 0, 0);
}

// ---------------------------------------------------------------------------
// Fused prep: all 12 weight transposes (fp32 [K][N] -> bf16 [N][K]) +
// x fp32 -> bf16 (r14: fp32 residual copy DROPPED — layer-0 addln reads x
// directly; cvt section widened to uint4 stores, 1024 blocks) + xpos table.
// Block ranges: [0,7168) wtrans, [7168,8192) cvt_x, [8192,8448) xpos_table.
// ---------------------------------------------------------------------------
__global__ __launch_bounds__(256) void prep_kernel(const float* __restrict__ x,
                                                   const float* __restrict__ Wq,
                                                   const float* __restrict__ Wk,
                                                   const float* __restrict__ Wv,
                                                   const float* __restrict__ Wo,
                                                   const float* __restrict__ W1,
                                                   const float* __restrict__ W2,
                                                   char* __restrict__ w,
                                                   u16* __restrict__ Ab,
                                                   float2* __restrict__ tab) {
    const size_t MB1 = 1u << 20;
    const int bid = blockIdx.x;
    const int tid = threadIdx.x;
    __shared__ float t[32][33];

    if (bid < 7168) {
        int l = bid / 3584;
        int tt = bid % 3584;
        u16* WqkvT = (u16*)(w + 48 * MB1 + (size_t)l * 2 * MB1);
        u16* WoT   = (u16*)(w + 52 * MB1 + (size_t)l * 1 * MB1);
        u16* W1T   = (u16*)(w + 54 * MB1 + (size_t)l * 2 * MB1);
        u16* W2T   = (u16*)(w + 58 * MB1 + (size_t)l * 2 * MB1);
        const float* src; u16* dst; int K, N, tix;
        if (tt < 256)       { src = Wq + (size_t)l * 512 * 512;  dst = WqkvT;              K = 512;  N = 512;  tix = tt; }
        else if (tt < 512)  { src = Wk + (size_t)l * 512 * 512;  dst = WqkvT + 512 * 512;  K = 512;  N = 512;  tix = tt - 256; }
        else if (tt < 1024) { src = Wv + (size_t)l * 512 * 1024; dst = WqkvT + 1024 * 512; K = 512;  N = 1024; tix = tt - 512; }
        else if (tt < 1536) { src = Wo + (size_t)l * 1024 * 512; dst = WoT;                K = 1024; N = 512;  tix = tt - 1024; }
        else if (tt < 2560) { src = W1 + (size_t)l * 512 * 2048; dst = W1T;                K = 512;  N = 2048; tix = tt - 1536; }
        else                { src = W2 + (size_t)l * 2048 * 512; dst = W2T;                K = 2048; N = 512;  tix = tt - 2560; }
        int ntx = N >> 5;
        int n0 = (tix % ntx) * 32, k0 = (tix / ntx) * 32;
        int tx = tid & 31, ty = tid >> 5;
#pragma unroll
        for (int i = 0; i < 4; i++)
            t[ty + 8 * i][tx] = src[(size_t)(k0 + ty + 8 * i) * N + n0 + tx];
        __syncthreads();
#pragma unroll
        for (int i = 0; i < 4; i++)
            dst[(size_t)(n0 + ty + 8 * i) * K + k0 + tx] = f2bf(t[tx][ty + 8 * i]);
    } else if (bid < 8192) {
        int i = ((bid - 7168) * 256 + tid) * 8;          // 2M elems, 8/thread
        float4 v0 = *(const float4*)(x + i);
        float4 v1 = *(const float4*)(x + i + 4);
        uint4 p;
        p.x = pk2bf(v0.x, v0.y);
        p.y = pk2bf(v0.z, v0.w);
        p.z = pk2bf(v1.x, v1.y);
        p.w = pk2bf(v1.z, v1.w);
        *(uint4*)(Ab + i) = p;
    } else {
        int idx = (bid - 8192) * 256 + tid;     // 65536 entries
        int j = idx & 31;
        int s = idx >> 5;
        float base = (2.0f * j + 0.4f * 64.0f) / (1.4f * 64.0f);
        float pos = (float)(s - 1024);
        float scale = powf(base, pos / SCALE_BASE);
        float inv_freq = powf(10000.0f, -(float)j / 32.0f);
        float ang = (float)s * inv_freq;
        tab[idx] = make_float2(cosf(ang) * scale, sinf(ang) * scale);
    }
}

// ---------------------------------------------------------------------------
// Fused xPos (in-place on Q,K cols of QKV; Q scaled by LOG2E) + V transpose
// (V cols of QKV -> VT) — column-disjoint, no intra-kernel ordering needed.
// Block ranges: [0,4096) xpos, [4096,5120) vtrans. (r11-validated.)
// ---------------------------------------------------------------------------
__global__ __launch_bounds__(256) void xpos_vtrans(u16* __restrict__ QKV,
                                                   const float2* __restrict__ tab,
                                                   u16* __restrict__ VT) {
    const int bid = blockIdx.x;
    const int tid = threadIdx.x;
    __shared__ u16 t[64][65];

    if (bid < 4096) {
        int idx = bid * 256 + tid;   // 2^20
        int j = idx & 31;
        int h = (idx >> 5) & 7;
        int s = (idx >> 8) & 2047;
        int b = idx >> 19;

        float2 cssn = tab[s * 32 + j];
        float cs = cssn.x, sn = cssn.y;

        size_t off = (size_t)(b * SLEN + s) * 2048 + h * 64 + 2 * j;
        u32* pq = (u32*)(QKV + off);
        u32* pk = (u32*)(QKV + off + 512);

        u32 qv = *pq;
        float q0 = bf2f((u16)(qv & 0xffff)), q1 = bf2f((u16)(qv >> 16));
        *pq = pk2bf((q0 * cs - q1 * sn) * LOG2E, (q1 * cs + q0 * sn) * LOG2E);

        u32 kv = *pk;
        float k0 = bf2f((u16)(kv & 0xffff)), k1 = bf2f((u16)(kv >> 16));
        *pk = pk2bf(k0 * cs - k1 * sn, k1 * cs + k0 * sn);
    } else {
        int v = bid - 4096;                 // 1024 blocks
        int bz = v & 15;                    // b*8 + h
        int vy = (v >> 4) & 1;              // v-tile
        int sx = v >> 5;                    // s-tile (32)
        int b = bz >> 3, h = bz & 7;
        int s0 = sx * 64, v0 = vy * 64;
#pragma unroll
        for (int i = 0; i < 16; i++) {
            int e = tid + i * 256; int r = e >> 6, c = e & 63;      // r: s, c: v
            t[r][c] = QKV[(size_t)(b * SLEN + s0 + r) * 2048 + 1024 + h * 128 + v0 + c];
        }
        __syncthreads();
#pragma unroll
        for (int i = 0; i < 16; i++) {
            int e = tid + i * 256; int r = e >> 6, c = e & 63;      // r: v, c: s
            VT[(size_t)((b * 8 + h) * 128 + v0 + r) * 2048 + s0 + c] = t[c][r];
        }
    }
}

// ---------------------------------------------------------------------------
// MFMA GEMM, software-pipelined, BK64, optional 2-way split-K (bias added by
// split 0 only). WT is [N][K] bf16. Split-K partials written BF16 (OUTF32=0)
// to halve partial write + addln read traffic. (r11-validated config.)
// ---------------------------------------------------------------------------
template <int BM, int BN, int BK, int WM, int OUTF32, int BIAS, int RELU,
          int NSPLIT, int WPE>
__global__ __launch_bounds__(256, WPE) void gemm_mfma(const u16* __restrict__ A,
                                                 const u16* __restrict__ WT,
                                                 const float* __restrict__ bias,
                                                 void* __restrict__ C0,
                                                 void* __restrict__ C1,
                                                 int M, int N, int K) {
    constexpr int WN  = 4 / WM;
    constexpr int AM  = BM / (WM * 16);
    constexpr int AN  = BN / (WN * 16);
    constexpr int KO  = BK / 32;
    constexpr int AIT = BM * BK / 2048;
    constexpr int BIT = BN * BK / 2048;
    constexpr int KB8 = BK / 8;

    __shared__ u16 As[2][BM * BK];
    __shared__ u16 Bs[2][BN * BK];

    const int tid  = threadIdx.x;
    const int wave = tid >> 6;
    const int lane = tid & 63;
    const int quad = lane >> 4;
    const int l15  = lane & 15;
    const int wm = wave % WM;
    const int wn = wave / WM;

    const int tm = blockIdx.y * BM;
    const int tn = blockIdx.x * BN;
    const int z  = (NSPLIT > 1) ? blockIdx.z : 0;
    const int Ksub = K / NSPLIT;
    const int k0g  = z * Ksub;

    auto issue = [&](int kt, int buf) {
#pragma unroll
        for (int it = 0; it < AIT; it++) {
            int cid = it * 256 + tid;
            async16(A + (size_t)(tm + cid / KB8) * K + k0g + kt + (cid % KB8) * 8,
                    (char*)As[buf] + (it * 256 + wave * 64) * 16);
        }
#pragma unroll
        for (int it = 0; it < BIT; it++) {
            int cid = it * 256 + tid;
            async16(WT + (size_t)(tn + cid / KB8) * K + k0g + kt + (cid % KB8) * 8,
                    (char*)Bs[buf] + (it * 256 + wave * 64) * 16);
        }
    };

    f32x4 acc[AM][AN];
#pragma unroll
    for (int i = 0; i < AM; i++)
#pragma unroll
        for (int j = 0; j < AN; j++) acc[i][j] = (f32x4){0.f, 0.f, 0.f, 0.f};

    const int nk = Ksub / BK;
    issue(0, 0);

    for (int t = 0; t < nk; t++) {
        __syncthreads();             // implicit vmcnt(0) drain: loads(t) done
        if (t + 1 < nk) issue((t + 1) * BK, (t + 1) & 1);
        const int buf = t & 1;

        bf16x8 af[KO][AM], bfr[KO][AN];
#pragma unroll
        for (int ko = 0; ko < KO; ko++) {
#pragma unroll
            for (int i = 0; i < AM; i++)
                af[ko][i] = *(const bf16x8*)((const char*)As[buf] +
                    (((wm * (AM * 16) + i * 16 + l15) * KB8) + ko * 4 + quad) * 16);
#pragma unroll
            for (int j = 0; j < AN; j++)
                bfr[ko][j] = *(const bf16x8*)((const char*)Bs[buf] +
                    (((wn * (AN * 16) + j * 16 + l15) * KB8) + ko * 4 + quad) * 16);
        }
#pragma unroll
        for (int ko = 0; ko < KO; ko++)
#pragma unroll
            for (int i = 0; i < AM; i++)
#pragma unroll
                for (int j = 0; j < AN; j++)
                    acc[i][j] = __builtin_amdgcn_mfma_f32_16x16x32_bf16(
                        af[ko][i], bfr[ko][j], acc[i][j], 0, 0, 0);
    }

    void* Cout = (NSPLIT > 1 && z) ? C1 : C0;
#pragma unroll
    for (int i = 0; i < AM; i++) {
#pragma unroll
        for (int j = 0; j < AN; j++) {
            int col = tn + wn * (AN * 16) + j * 16 + l15;
            float bv = (BIAS && z == 0) ? bias[col] : 0.0f;
#pragma unroll
            for (int r = 0; r < 4; r++) {
                int row = tm + wm * (AM * 16) + i * 16 + quad * 4 + r;
                float v = acc[i][j][r] + bv;
                if (RELU) v = fmaxf(v, 0.0f);
                if (OUTF32) ((float*)Cout)[(size_t)row * N + col] = v;
                else        ((u16*)Cout)[(size_t)row * N + col] = f2bf(v);
            }
        }
    }
}

// ---------------------------------------------------------------------------
// MFMA flash attention v12 (validated 53.5-56us): 32x32 MFMA, permlane
// P-build, 2-buffer + __syncthreads, cvt_pk, tree reductions, 3-way split-K.
// At its structural floor (r9: +50% occupancy -> flat). Unchanged.
// ---------------------------------------------------------------------------
__global__ __launch_bounds__(256, 3) void flash_attn_mfma(const u16* __restrict__ QKV,
                                                          const u16* __restrict__ VT,
                                                          u16* __restrict__ OP0,
                                                          u16* __restrict__ OP1,
                                                          u16* __restrict__ OP2,
                                                          float* __restrict__ MLW) {
    const int h  = blockIdx.x;           // XCD swizzle: x = head
    const int q0 = blockIdx.y * 128;
    const int bz = blockIdx.z;           // b*3 + split
    const int b  = bz / 3;
    const int split = bz - b * 3;
    const int tid  = threadIdx.x;
    const int wave = tid >> 6;
    const int lane = tid & 63;
    const int l31  = lane & 31;
    const int hi   = lane >> 5;
    const int swz  = (l31 & 7) ^ ((l31 >> 3) << 1);   // S(row) for row=l31 mod 32

    __shared__ u16 Ks[2][64 * 64];   // [row=key 0..63][64 d], 128B rows
    __shared__ u16 Vs[2][128 * 64];  // [row=v 0..127][64 keys] (48 KB total)

    const int tcnt = (split == 2) ? 10 : 11;   // 11+11+10 = 32 tiles of 64
    const int kb0  = split * 704;              // 11*64

    // hoisted per-thread staging source pointers (rule #21 inverse swizzle)
    const u16* kp[2];
    const u16* vp[4];
#pragma unroll
    for (int it = 0; it < 2; it++) {
        int cid = it * 256 + tid;            // 512 chunks = 64 rows x 8
        int row = cid >> 3;
        int lc  = (cid & 7) ^ (row & 7) ^ (((row >> 3) & 3) << 1);
        kp[it] = QKV + (size_t)(b * SLEN + kb0 + row) * 2048 + 512 + h * 64 + lc * 8;
    }
#pragma unroll
    for (int it = 0; it < 4; it++) {
        int cid = it * 256 + tid;            // 1024 chunks = 128 rows x 8
        int row = cid >> 3;
        int lc  = (cid & 7) ^ (row & 7) ^ (((row >> 3) & 3) << 1);
        vp[it] = VT + (size_t)((b * 8 + h) * 128 + row) * 2048 + kb0 + lc * 8;
    }

    auto issueKV = [&](int buf) {
#pragma unroll
        for (int it = 0; it < 2; it++) {
            async16(kp[it], (char*)Ks[buf] + (it * 256 + wave * 64) * 16);
            kp[it] += 64 * 2048;             // next 64-key tile
        }
#pragma unroll
        for (int it = 0; it < 4; it++) {
            async16(vp[it], (char*)Vs[buf] + (it * 256 + wave * 64) * 16);
            vp[it] += 64;                    // next 64-key column chunk
        }
    };

    // Q B-fragments: col=q=l31 (row q0+wave*32+l31), k-chunk hi: 4 d-chunks
    bf16x8 qf[4];
    {
        const u16* p = QKV + (size_t)(b * SLEN + q0 + wave * 32 + l31) * 2048 +
                       h * 64 + hi * 8;
#pragma unroll
        for (int dc = 0; dc < 4; dc++) qf[dc] = *(const bf16x8*)(p + dc * 16);
    }

    f32x16 o_acc[4];   // o_acc[rb][reg] = O^T[v=rb*32+crow(reg,hi)][q=l31]
#pragma unroll
    for (int rb = 0; rb < 4; rb++)
#pragma unroll
        for (int r = 0; r < 16; r++) o_acc[rb][r] = 0.f;
    float m = -1e30f;
    float l = 0.f;

    issueKV(0);

    for (int ti = 0; ti < tcnt; ti++) {
        __syncthreads();                 // implicit vmcnt(0): tiles(ti) landed
        if (ti + 1 < tcnt) issueKV((ti + 1) & 1);
        const int buf = ti & 1;

        // S^T = K x Q : st[kb][reg] = S[key=kb*32+crow(reg,hi)][q=l31]
        f32x16 st[2];
#pragma unroll
        for (int kb = 0; kb < 2; kb++)
#pragma unroll
            for (int r = 0; r < 16; r++) st[kb][r] = 0.f;
        __builtin_amdgcn_s_setprio(1);
#pragma unroll
        for (int dc = 0; dc < 4; dc++)
#pragma unroll
            for (int kb = 0; kb < 2; kb++) {
                bf16x8 kf = *(const bf16x8*)((const char*)Ks[buf] +
                    ((kb * 32 + l31) * 8 + ((dc * 2 + hi) ^ swz)) * 16);
                st[kb] = __builtin_amdgcn_mfma_f32_32x32x16_bf16(kf, qf[dc],
                                                                 st[kb], 0, 0, 0);
            }
        __builtin_amdgcn_s_setprio(0);

        // softmax max: pairwise tree (depth 5) + one cross-half exchange
        float fm[16];
#pragma unroll
        for (int r = 0; r < 16; r++) fm[r] = fmaxf(st[0][r], st[1][r]);
#pragma unroll
        for (int s = 8; s > 0; s >>= 1)
#pragma unroll
            for (int r = 0; r < s; r++) fm[r] = fmaxf(fm[r], fm[r + s]);
        float mx = fmaxf(fm[0], __shfl_xor(fm[0], 32, 64));

        float mnew = fmaxf(m, mx);
        float alpha = exp2f(m - mnew);
        m = mnew;

        // exp + 4-chain sum (depth 8)
        float s0 = 0.f, s1 = 0.f, s2 = 0.f, s3 = 0.f;
#pragma unroll
        for (int kb = 0; kb < 2; kb++)
#pragma unroll
            for (int r = 0; r < 16; r += 4) {
                float p0 = exp2f(st[kb][r + 0] - mnew);
                float p1 = exp2f(st[kb][r + 1] - mnew);
                float p2 = exp2f(st[kb][r + 2] - mnew);
                float p3 = exp2f(st[kb][r + 3] - mnew);
                st[kb][r + 0] = p0; st[kb][r + 1] = p1;
                st[kb][r + 2] = p2; st[kb][r + 3] = p3;
                s0 += p0; s1 += p1; s2 += p2; s3 += p3;
            }
        float ls = (s0 + s1) + (s2 + s3);
        ls += __shfl_xor(ls, 32, 64);
        l = l * alpha + ls;

        // rescale O^T (alpha uniform across the lane's q column)
#pragma unroll
        for (int rb = 0; rb < 4; rb++)
#pragma unroll
            for (int r = 0; r < 16; r++) o_acc[rb][r] *= alpha;

        // PV: B-frag = P^T[key][q] built via cvt_pk + permlane32_swap (T12)
#pragma unroll
        for (int kc = 0; kc < 4; kc++) {
            const int kb = kc >> 1, o = (kc & 1) * 8;
            u32 a1 = cvtpk(st[kb][o + 0], st[kb][o + 1]);
            u32 b1 = cvtpk(st[kb][o + 4], st[kb][o + 5]);
            u32 a2 = cvtpk(st[kb][o + 2], st[kb][o + 3]);
            u32 b2 = cvtpk(st[kb][o + 6], st[kb][o + 7]);
            asm volatile("v_permlane32_swap_b32 %0, %1" : "+v"(a1), "+v"(b1));
            asm volatile("v_permlane32_swap_b32 %0, %1" : "+v"(a2), "+v"(b2));
            union { u32 u[4]; bf16x8 v; } pf;
            pf.u[0] = a1; pf.u[1] = a2; pf.u[2] = b1; pf.u[3] = b2;
            __builtin_amdgcn_s_setprio(1);
#pragma unroll
            for (int rb = 0; rb < 4; rb++) {
                bf16x8 vb = *(const bf16x8*)((const char*)Vs[buf] +
                    ((rb * 32 + l31) * 8 + ((kc * 2 + hi) ^ swz)) * 16);
                o_acc[rb] = __builtin_amdgcn_mfma_f32_32x32x16_bf16(vb, pf.v,
                                                                    o_acc[rb], 0, 0, 0);
            }
            __builtin_amdgcn_s_setprio(0);
        }
    }

    // epilogue: write l-normalized partial O/l; scalar logw = m + log2(l).
    const int q = q0 + wave * 32 + l31;
    if (lane < 32)
        MLW[((size_t)(b * 3 + split) * 8 + h) * 2048 + q] = m + __log2f(l);
    const float invl = 1.0f / l;
    u16* OP = (split == 0) ? OP0 : ((split == 1) ? OP1 : OP2);
    const size_t rstride = (split == 2) ? 2048 : 1024;   // OP2 = QKV V-cols
    size_t rowbase = ((size_t)(b * SLEN + q)) * rstride + h * 128;
#pragma unroll
    for (int rb = 0; rb < 4; rb++)
#pragma unroll
        for (int i = 0; i < 8; i++) {
            int v = rb * 32 + ((2 * i) & 3) + 8 * (i >> 1) + 4 * hi;
            *(u32*)(OP + rowbase + v) =
                pk2bf(o_acc[rb][2 * i] * invl, o_acc[rb][2 * i + 1] * invl);
        }
}

// ---------------------------------------------------------------------------
// Merge the three l-normalized split-K partials (8 elems/thread, uint4):
// out = ATT_SCALING * Sum_s O_s * 2^(logw_s - M) / Sum_s 2^(logw_s - M)
// P2 is strided (QKV V-columns, row stride 2048).
// ---------------------------------------------------------------------------
__global__ __launch_bounds__(256) void attn_combine(const u16* __restrict__ P0,
                                                    const u16* __restrict__ P1,
                                                    const u16* __restrict__ P2,
                                                    const float* __restrict__ MLW,
                                                    u16* __restrict__ AT) {
    int idx = (blockIdx.x * 256 + threadIdx.x) * 8;   // 4096*1024 total
    int col = idx & 1023;
    int row = idx >> 10;                        // b*2048 + q
    int h = col >> 7;
    int b = row >> 11, q = row & 2047;
    float g0 = MLW[((size_t)(b * 3 + 0) * 8 + h) * 2048 + q];
    float g1 = MLW[((size_t)(b * 3 + 1) * 8 + h) * 2048 + q];
    float g2 = MLW[((size_t)(b * 3 + 2) * 8 + h) * 2048 + q];
    float M = fmaxf(g0, fmaxf(g1, g2));
    float e0 = exp2f(g0 - M), e1 = exp2f(g1 - M), e2 = exp2f(g2 - M);
    float norm = ATT_SCALING / (e0 + e1 + e2);
    e0 *= norm; e1 *= norm; e2 *= norm;

    uint4 a = *(const uint4*)(P0 + idx);
    uint4 c = *(const uint4*)(P1 + idx);
    uint4 d = *(const uint4*)(P2 + (size_t)row * 2048 + col);
    uint4 o;
    u32 au[4] = {a.x, a.y, a.z, a.w};
    u32 cu[4] = {c.x, c.y, c.z, c.w};
    u32 du[4] = {d.x, d.y, d.z, d.w};
    u32 ou[4];
#pragma unroll
    for (int k = 0; k < 4; k++) {
        float r0 = bf2f((u16)(au[k] & 0xffff)) * e0 + bf2f((u16)(cu[k] & 0xffff)) * e1 +
                   bf2f((u16)(du[k] & 0xffff)) * e2;
        float r1 = bf2f((u16)(au[k] >> 16)) * e0 + bf2f((u16)(cu[k] >> 16)) * e1 +
                   bf2f((u16)(du[k] >> 16)) * e2;
        ou[k] = pk2bf(r0, r1);
    }
    o.x = ou[0]; o.y = ou[1]; o.z = ou[2]; o.w = ou[3];
    *(uint4*)(AT + idx) = o;
}

// ---------------------------------------------------------------------------
// LN(X + R0 + R1) * g + be : X fp32, R0/R1 BF16 split-K partials, fp32 +
// bf16 out. One wave per row (lane owns 8 cols), float4/uint4 loads,
// shfl_xor reductions, zero LDS / barriers.
// ---------------------------------------------------------------------------
__global__ __launch_bounds__(256) void addln_kernel(const float* __restrict__ X,
                                                    const u16* __restrict__ R0,
                                                    const u16* __restrict__ R1,
                                                    const float* __restrict__ g,
                                                    const float* __restrict__ be,
                                                    float* __restrict__ dstf,
                                                    u16* __restrict__ dstb) {
    const int tid  = threadIdx.x;
    const int wave = tid >> 6;
    const int lane = tid & 63;
    const int row  = blockIdx.x * 4 + wave;
    size_t off = (size_t)row * HIDDEN + lane * 8;

    float4 a0 = *(const float4*)(X + off),  a1 = *(const float4*)(X + off + 4);
    uint4 p = *(const uint4*)(R0 + off);
    uint4 q = *(const uint4*)(R1 + off);
    u32 pu[4] = {p.x, p.y, p.z, p.w};
    u32 qu[4] = {q.x, q.y, q.z, q.w};
    float v[8];
    v[0] = a0.x + bf2f((u16)(pu[0] & 0xffff)) + bf2f((u16)(qu[0] & 0xffff));
    v[1] = a0.y + bf2f((u16)(pu[0] >> 16))    + bf2f((u16)(qu[0] >> 16));
    v[2] = a0.z + bf2f((u16)(pu[1] & 0xffff)) + bf2f((u16)(qu[1] & 0xffff));
    v[3] = a0.w + bf2f((u16)(pu[1] >> 16))    + bf2f((u16)(qu[1] >> 16));
    v[4] = a1.x + bf2f((u16)(pu[2] & 0xffff)) + bf2f((u16)(qu[2] & 0xffff));
    v[5] = a1.y + bf2f((u16)(pu[2] >> 16))    + bf2f((u16)(qu[2] >> 16));
    v[6] = a1.z + bf2f((u16)(pu[3] & 0xffff)) + bf2f((u16)(qu[3] & 0xffff));
    v[7] = a1.w + bf2f((u16)(pu[3] >> 16))    + bf2f((u16)(qu[3] >> 16));

    float s = ((v[0] + v[1]) + (v[2] + v[3])) + ((v[4] + v[5]) + (v[6] + v[7]));
#pragma unroll
    for (int d = 1; d < 64; d <<= 1) s += __shfl_xor(s, d, 64);
    float mu = s * (1.0f / HIDDEN);

    float t = 0.f;
#pragma unroll
    for (int j = 0; j < 8; j++) { float dv = v[j] - mu; v[j] = dv; t += dv * dv; }
#pragma unroll
    for (int d = 1; d < 64; d <<= 1) t += __shfl_xor(t, d, 64);
    float rstd = rsqrtf(t * (1.0f / HIDDEN) + LN_EPS);

    float4 g0 = *(const float4*)(g + lane * 8),  g1 = *(const float4*)(g + lane * 8 + 4);
    float4 b0 = *(const float4*)(be + lane * 8), b1 = *(const float4*)(be + lane * 8 + 4);
    float o[8];
    o[0] = v[0] * rstd * g0.x + b0.x; o[1] = v[1] * rstd * g0.y + b0.y;
    o[2] = v[2] * rstd * g0.z + b0.z; o[3] = v[3] * rstd * g0.w + b0.w;
    o[4] = v[4] * rstd * g1.x + b1.x; o[5] = v[5] * rstd * g1.y + b1.y;
    o[6] = v[6] * rstd * g1.z + b1.z; o[7] = v[7] * rstd * g1.w + b1.w;

    *(float4*)(dstf + off)     = make_float4(o[0], o[1], o[2], o[3]);
    *(float4*)(dstf + off + 4) = make_float4(o[4], o[5], o[6], o[7]);
    uint4 ob;
    ob.x = pk2bf(o[0], o[1]); ob.y = pk2bf(o[2], o[3]);
    ob.z = pk2bf(o[4], o[5]); ob.w = pk2bf(o[6], o[7]);
    *(uint4*)(dstb + off) = ob;
}

// ---------------------------------------------------------------------------
extern "C" void kernel_launch(void* const* d_in, const int* in_sizes, int n_in,
                              void* d_out, int out_size, void* d_ws, size_t ws_size,
                              hipStream_t stream) {
    const float* x   = (const float*)d_in[0];
    const float* Wq  = (const float*)d_in[1];
    const float* Wk  = (const float*)d_in[2];
    const float* Wv  = (const float*)d_in[3];
    const float* Wo  = (const float*)d_in[4];
    const float* W1  = (const float*)d_in[5];
    const float* b1  = (const float*)d_in[6];
    const float* W2  = (const float*)d_in[7];
    const float* b2  = (const float*)d_in[8];
    const float* g1  = (const float*)d_in[9];
    const float* be1 = (const float*)d_in[10];
    const float* g2  = (const float*)d_in[11];
    const float* be2 = (const float*)d_in[12];
    float* out = (float*)d_out;

    // Workspace (63 MB):
    //  0-8   : R1f residual (fp32; layer-0 residual read comes from x itself)
    //  8-16  : VTg -> Yf
    //  16-20 : OP1 -> PfA(bf16) -> F2a(bf16)
    //  20-24 : PfB(bf16) -> F2b(bf16)
    //  24-40 : QKV (V-cols double as OP2) -> F1
    //  40-48 : A_bf(40-44) -> OP0/AT -> Y_bf(40-44) -> A_bf
    //  48-62 : bf16 transposed weights ; 62-62.5 : xtab ; 62.5-63: MLW (384KB)
    const size_t MB = 1u << 20;
    char* w = (char*)d_ws;
    float*  R1f  = (float*)(w);
    u16*    VTg  = (u16*)(w + 8 * MB);
    float*  Yf   = (float*)(w + 8 * MB);
    u16*    OP1  = (u16*)(w + 16 * MB);
    u16*    PfA  = (u16*)(w + 16 * MB);
    u16*    F2a  = (u16*)(w + 16 * MB);
    u16*    PfB  = (u16*)(w + 20 * MB);
    u16*    F2b  = (u16*)(w + 20 * MB);
    u16*    QKV  = (u16*)(w + 24 * MB);
    u16*    F1   = (u16*)(w + 24 * MB);
    u16*    A_bf = (u16*)(w + 40 * MB);
    u16*    OP0  = (u16*)(w + 40 * MB);
    u16*    AT   = (u16*)(w + 40 * MB);
    u16*    Y_bf = (u16*)(w + 40 * MB);
    float2* xtab = (float2*)(w + 62 * MB);
    float*  MLW  = (float*)(w + 62 * MB + 512 * 1024);
    u16*    OP2  = QKV + 1024;           // dead V-columns, row stride 2048

    // One fused prep dispatch: 12 weight transposes + x->bf16 + xpos table
    // (r14: fp32 x copy dropped; 8448 blocks, was 9472)
    prep_kernel<<<8448, 256, 0, stream>>>(x, Wq, Wk, Wv, Wo, W1, W2,
                                          w, A_bf, xtab);

    for (int l = 0; l < LAYERS; l++) {
        u16* WqkvT = (u16*)(w + 48 * MB + (size_t)l * 2 * MB);
        u16* WoT   = (u16*)(w + 52 * MB + (size_t)l * 1 * MB);
        u16* W1T   = (u16*)(w + 54 * MB + (size_t)l * 2 * MB);
        u16* W2T   = (u16*)(w + 58 * MB + (size_t)l * 2 * MB);
        const float* b1_l  = b1 + (size_t)l * FFN_DIM;
        const float* b2_l  = b2 + (size_t)l * HIDDEN;
        const float* g1_l  = g1 + (size_t)l * HIDDEN;
        const float* be1_l = be1 + (size_t)l * HIDDEN;
        const float* g2_l  = g2 + (size_t)l * HIDDEN;
        const float* be2_l = be2 + (size_t)l * HIDDEN;

        // QKV = A_bf @ [Wq|Wk|Wv]  (bf16 out), 128x128 BK64, 512 blocks
        gemm_mfma<128, 128, 64, 2, 0, 0, 0, 1, 2><<<dim3(16, 32), 256, 0, stream>>>(
            A_bf, WqkvT, nullptr, QKV, nullptr, MROWS, 2048, 512);

        // fused xpos (Q,K) + V transpose
        xpos_vtrans<<<5120, 256, 0, stream>>>(QKV, xtab, VTg);

        // flash attention: 3-way split-K, grid (h, qtile, b*3+split) = 768
        flash_attn_mfma<<<dim3(8, 16, 6), 256, 0, stream>>>(QKV, VTg, OP0, OP1,
                                                            OP2, MLW);
        attn_combine<<<MROWS * 1024 / 2048, 256, 0, stream>>>(OP0, OP1, OP2,
                                                              MLW, AT);

        // P = AT @ Wo: 128x64 BK64, 2-way split-K -> BF16 partials
        gemm_mfma<128, 64, 64, 2, 0, 0, 0, 2, 2><<<dim3(8, 32, 2), 256, 0, stream>>>(
            AT, WoT, nullptr, PfA, PfB, MROWS, 512, 1024);

        // Y = LN(A + P0 + P1); layer 0 reads x directly as the residual
        const float* Xres = (l == 0) ? x : R1f;
        addln_kernel<<<MROWS / 4, 256, 0, stream>>>(Xres, PfA, PfB, g1_l, be1_l, Yf, Y_bf);

        // F1 = relu(Y @ W1 + b1) (bf16 out), 128x128 BK64
        gemm_mfma<128, 128, 64, 2, 0, 1, 1, 1, 2><<<dim3(16, 32), 256, 0, stream>>>(
            Y_bf, W1T, b1_l, F1, nullptr, MROWS, 2048, 512);

        // F2 = F1 @ W2 + b2: 128x64 BK64, 2-way split-K -> BF16 partials
        gemm_mfma<128, 64, 64, 2, 0, 1, 0, 2, 2><<<dim3(8, 32, 2), 256, 0, stream>>>(
            F1, W2T, b2_l, F2a, F2b, MROWS, 512, 2048);

        // x_next = LN(Y + F2a + F2b), wave-per-row
        float* dstf = (l == LAYERS - 1) ? out : R1f;
        addln_kernel<<<MROWS / 4, 256, 0, stream>>>(Yf, F2a, F2b, g2_l, be2_l, dstf, A_bf);
    }
}